// Round 1
// baseline (643.816 us; speedup 1.0000x reference)
//
#include <hip/hip_runtime.h>
#include <hip/hip_bf16.h>

// MoE top-2 router + grouped SwiGLU experts, MI355X gfx950.
// T=8192 tokens, D=1024, E=8, F=512, top-k=2. fp32 in/out, bf16 MFMA compute.

typedef __attribute__((ext_vector_type(4))) float  f32x4;
typedef __attribute__((ext_vector_type(8))) unsigned short us8;
typedef __attribute__((ext_vector_type(4))) unsigned short us4;
typedef __bf16 bf16_t;
typedef __attribute__((ext_vector_type(8))) bf16_t bf16x8;

#define TTOK 8192
#define DDIM 1024
#define EEXP 8
#define FDIM 512

__device__ __forceinline__ unsigned short f2bf(float f) {
  unsigned int u = __float_as_uint(f);
  u = (u + 0x7FFFu + ((u >> 16) & 1u)) >> 16;   // RNE
  return (unsigned short)u;
}

// ---------------- convert x fp32 -> bf16 (8 elems/thread) ----------------
__global__ __launch_bounds__(256) void k_cvt_x(const float* __restrict__ x,
                                               unsigned short* __restrict__ xb) {
  int i = blockIdx.x * 256 + threadIdx.x;            // grid sized exactly T*D/8
  const f32x4* s = (const f32x4*)x + (size_t)i * 2;
  f32x4 a = s[0], b = s[1];
  us8 o;
  o[0]=f2bf(a[0]); o[1]=f2bf(a[1]); o[2]=f2bf(a[2]); o[3]=f2bf(a[3]);
  o[4]=f2bf(b[0]); o[5]=f2bf(b[1]); o[6]=f2bf(b[2]); o[7]=f2bf(b[3]);
  *((us8*)xb + i) = o;
}

// ---- transpose+convert: src fp32 [e][M][N] -> dst bf16 [e][N][M] ----
__global__ __launch_bounds__(256) void k_tcvt(const float* __restrict__ src,
                                              unsigned short* __restrict__ dst,
                                              int M, int N) {
  __shared__ float tile[32][33];
  int e  = blockIdx.z;
  int m0 = blockIdx.y * 32, n0 = blockIdx.x * 32;
  const float* s = src + (size_t)e * M * N;
  unsigned short* d = dst + (size_t)e * M * N;
  int r  = threadIdx.x >> 3;
  int c4 = (threadIdx.x & 7) * 4;
  f32x4 v = *(const f32x4*)(s + (size_t)(m0 + r) * N + n0 + c4);
  tile[r][c4+0] = v[0]; tile[r][c4+1] = v[1];
  tile[r][c4+2] = v[2]; tile[r][c4+3] = v[3];
  __syncthreads();
  us4 o;
  o[0] = f2bf(tile[c4+0][r]); o[1] = f2bf(tile[c4+1][r]);
  o[2] = f2bf(tile[c4+2][r]); o[3] = f2bf(tile[c4+3][r]);
  *(us4*)(d + (size_t)(n0 + r) * M + m0 + c4) = o;
}

// ---------------- router: logits (fp64 acc), top-2, renorm ----------------
__global__ __launch_bounds__(256) void k_router(const float* __restrict__ x,
                                                const float* __restrict__ rw,
                                                int* __restrict__ topki,
                                                float* __restrict__ topkw,
                                                int* __restrict__ ctrs) {
  int t    = blockIdx.x * 4 + (threadIdx.x >> 6);    // wave per token
  int lane = threadIdx.x & 63;
  const f32x4* xr = (const f32x4*)(x + (size_t)t * DDIM);
  const f32x4* wr = (const f32x4*)rw;
  double p[8];
  #pragma unroll
  for (int e = 0; e < 8; ++e) p[e] = 0.0;
  #pragma unroll
  for (int c = 0; c < 4; ++c) {
    f32x4 xv = xr[c * 64 + lane];
    #pragma unroll
    for (int e = 0; e < 8; ++e) {
      f32x4 wv = wr[e * 256 + c * 64 + lane];
      p[e] += (double)xv[0]*wv[0] + (double)xv[1]*wv[1]
            + (double)xv[2]*wv[2] + (double)xv[3]*wv[3];
    }
  }
  #pragma unroll
  for (int e = 0; e < 8; ++e) {
    #pragma unroll
    for (int off = 32; off >= 1; off >>= 1)
      p[e] += __shfl_xor(p[e], off, 64);
  }
  if (lane == 0) {
    int i1 = 0;
    #pragma unroll
    for (int e2 = 1; e2 < 8; ++e2) if (p[e2] > p[i1]) i1 = e2;
    int i2 = (i1 == 0) ? 1 : 0;
    #pragma unroll
    for (int e2 = 0; e2 < 8; ++e2) if (e2 != i1 && p[e2] > p[i2]) i2 = e2;
    // renormalized top-2 of softmax == softmax over the 2 selected logits
    float d21 = (float)(p[i2] - p[i1]);
    float e1  = __expf(d21);
    float s   = 1.f + e1;
    topki[2*t]   = i1;       topki[2*t+1] = i2;
    topkw[2*t]   = 1.f / s;  topkw[2*t+1] = e1 / s;
    atomicAdd(&ctrs[i1], 1);
    atomicAdd(&ctrs[i2], 1);
  }
}

// ctrs layout (ints): [0..7]=counts  [8..16]=offsets  [17..24]=pos
__global__ void k_scan(int* __restrict__ ctrs) {
  if (threadIdx.x == 0 && blockIdx.x == 0) {
    ctrs[8] = 0;
    #pragma unroll
    for (int e = 0; e < 8; ++e) ctrs[9 + e] = ctrs[8 + e] + ctrs[e];
    #pragma unroll
    for (int e = 0; e < 8; ++e) ctrs[17 + e] = 0;
  }
}

__global__ __launch_bounds__(256) void k_scatter(const int* __restrict__ topki,
                                                 const float* __restrict__ topkw,
                                                 int* __restrict__ ctrs,
                                                 int* __restrict__ at,
                                                 float* __restrict__ aw) {
  int t = blockIdx.x * 256 + threadIdx.x;
  #pragma unroll
  for (int k = 0; k < 2; ++k) {
    int e = topki[2*t + k];
    int p = atomicAdd(&ctrs[17 + e], 1);
    int a = ctrs[8 + e] + p;
    at[a] = t;
    aw[a] = topkw[2*t + k];
  }
}

// -------- grouped GEMM 1: h = silu(x@wg) * (x@wu), per-expert segments -----
// tile 32(rows) x 128(f), BK=64, MFMA 16x16x32 bf16, XOR-swizzled LDS.
__global__ __launch_bounds__(256) void k_gateup(
    const unsigned short* __restrict__ xb,   // [T][D] bf16
    const unsigned short* __restrict__ wgt,  // [E][F][D] bf16 (transposed)
    const unsigned short* __restrict__ wut,  // [E][F][D]
    const int* __restrict__ at,
    const int* __restrict__ ctrs,
    unsigned short* __restrict__ h) {        // [2T][F] bf16
  int e    = blockIdx.z;
  int seg0 = ctrs[8 + e];
  int cnt  = ctrs[9 + e] - seg0;
  int row0 = blockIdx.y * 32;
  if (row0 >= cnt) return;                   // early-exit inactive tiles
  int f0 = blockIdx.x * 128;

  __shared__ unsigned short lA [32 * 64];    // [row][k], 16B-unit XOR swizzle
  __shared__ unsigned short lBg[128 * 64];   // [n][k]
  __shared__ unsigned short lBu[128 * 64];

  int tid = threadIdx.x;
  int arow = tid >> 3, aunit = tid & 7;
  int rg   = row0 + arow;
  int tokA = at[seg0 + ((rg < cnt) ? rg : 0)];     // dummy = segment row 0
  const unsigned short* srcA = xb + (size_t)tokA * DDIM + aunit * 8;
  int laOff = (arow * 8 + (aunit ^ (arow & 7))) * 8;

  int w = tid >> 6, lane = tid & 63;
  int m0w = (w & 1) * 16, n0w = (w >> 1) * 64;

  f32x4 zero = {0.f, 0.f, 0.f, 0.f};
  f32x4 accg[4], accu[4];
  #pragma unroll
  for (int nt = 0; nt < 4; ++nt) { accg[nt] = zero; accu[nt] = zero; }

  const unsigned short* bgBase = wgt + ((size_t)e * FDIM + f0) * DDIM;
  const unsigned short* buBase = wut + ((size_t)e * FDIM + f0) * DDIM;

  for (int ks = 0; ks < DDIM / 64; ++ks) {
    int k0 = ks * 64;
    *(us8*)&lA[laOff] = *(const us8*)(srcA + k0);
    #pragma unroll
    for (int i = 0; i < 4; ++i) {
      int lin = tid + i * 256;
      int br = lin >> 3, bu = lin & 7;
      int off = (br * 8 + (bu ^ (br & 7))) * 8;
      size_t goff = (size_t)br * DDIM + k0 + bu * 8;
      *(us8*)&lBg[off] = *(const us8*)(bgBase + goff);
      *(us8*)&lBu[off] = *(const us8*)(buBase + goff);
    }
    __syncthreads();
    #pragma unroll
    for (int kk = 0; kk < 2; ++kk) {
      int ar = m0w + (lane & 15);
      int au = (kk * 4 + (lane >> 4)) ^ (ar & 7);
      bf16x8 af = *(const bf16x8*)&lA[(ar * 8 + au) * 8];
      #pragma unroll
      for (int nt = 0; nt < 4; ++nt) {
        int br = n0w + nt * 16 + (lane & 15);
        int bu = (kk * 4 + (lane >> 4)) ^ (br & 7);
        bf16x8 bg  = *(const bf16x8*)&lBg[(br * 8 + bu) * 8];
        bf16x8 buf = *(const bf16x8*)&lBu[(br * 8 + bu) * 8];
        accg[nt] = __builtin_amdgcn_mfma_f32_16x16x32_bf16(af, bg,  accg[nt], 0, 0, 0);
        accu[nt] = __builtin_amdgcn_mfma_f32_16x16x32_bf16(af, buf, accu[nt], 0, 0, 0);
      }
    }
    __syncthreads();
  }
  // epilogue: silu(g)*u -> h (C layout: col=lane&15, row=(lane>>4)*4+j)
  #pragma unroll
  for (int nt = 0; nt < 4; ++nt) {
    #pragma unroll
    for (int j = 0; j < 4; ++j) {
      int rl = m0w + (lane >> 4) * 4 + j;
      if (row0 + rl < cnt) {
        float g = accg[nt][j], u = accu[nt][j];
        float hv = g * (1.f / (1.f + __expf(-g))) * u;
        h[(size_t)(seg0 + row0 + rl) * FDIM + f0 + n0w + nt * 16 + (lane & 15)] = f2bf(hv);
      }
    }
  }
}

// -------- grouped GEMM 2: out[tok] += w * (h @ w_down[e]) ------------------
__global__ __launch_bounds__(256) void k_down(
    const unsigned short* __restrict__ h,    // [2T][F] bf16
    const unsigned short* __restrict__ wdt,  // [E][D][F] bf16 (transposed)
    const int* __restrict__ at,
    const float* __restrict__ aw,
    const int* __restrict__ ctrs,
    float* __restrict__ out) {               // [T][D] fp32 (zeroed)
  int e    = blockIdx.z;
  int seg0 = ctrs[8 + e];
  int cnt  = ctrs[9 + e] - seg0;
  int row0 = blockIdx.y * 32;
  if (row0 >= cnt) return;
  int d0 = blockIdx.x * 128;

  __shared__ unsigned short lA[32 * 64];
  __shared__ unsigned short lB[128 * 64];
  __shared__ int   s_tok[32];
  __shared__ float s_w[32];

  int tid = threadIdx.x;
  if (tid < 32) {
    int rg = row0 + tid;
    int a  = seg0 + ((rg < cnt) ? rg : 0);
    s_tok[tid] = at[a];
    s_w[tid]   = aw[a];
  }
  int arow = tid >> 3, aunit = tid & 7;
  int rg = row0 + arow;
  const unsigned short* srcA = h + (size_t)(seg0 + ((rg < cnt) ? rg : 0)) * FDIM + aunit * 8;
  int laOff = (arow * 8 + (aunit ^ (arow & 7))) * 8;

  int w = tid >> 6, lane = tid & 63;
  int m0w = (w & 1) * 16, n0w = (w >> 1) * 64;

  f32x4 zero = {0.f, 0.f, 0.f, 0.f};
  f32x4 acc[4];
  #pragma unroll
  for (int nt = 0; nt < 4; ++nt) acc[nt] = zero;

  const unsigned short* bBase = wdt + ((size_t)e * DDIM + d0) * FDIM;

  for (int ks = 0; ks < FDIM / 64; ++ks) {
    int k0 = ks * 64;
    *(us8*)&lA[laOff] = *(const us8*)(srcA + k0);
    #pragma unroll
    for (int i = 0; i < 4; ++i) {
      int lin = tid + i * 256;
      int br = lin >> 3, bu = lin & 7;
      int off = (br * 8 + (bu ^ (br & 7))) * 8;
      *(us8*)&lB[off] = *(const us8*)(bBase + (size_t)br * FDIM + k0 + bu * 8);
    }
    __syncthreads();
    #pragma unroll
    for (int kk = 0; kk < 2; ++kk) {
      int ar = m0w + (lane & 15);
      int au = (kk * 4 + (lane >> 4)) ^ (ar & 7);
      bf16x8 af = *(const bf16x8*)&lA[(ar * 8 + au) * 8];
      #pragma unroll
      for (int nt = 0; nt < 4; ++nt) {
        int br = n0w + nt * 16 + (lane & 15);
        int bu = (kk * 4 + (lane >> 4)) ^ (br & 7);
        bf16x8 bf = *(const bf16x8*)&lB[(br * 8 + bu) * 8];
        acc[nt] = __builtin_amdgcn_mfma_f32_16x16x32_bf16(af, bf, acc[nt], 0, 0, 0);
      }
    }
    __syncthreads();
  }
  #pragma unroll
  for (int nt = 0; nt < 4; ++nt) {
    #pragma unroll
    for (int j = 0; j < 4; ++j) {
      int rl = m0w + (lane >> 4) * 4 + j;
      if (row0 + rl < cnt) {
        float v = acc[nt][j] * s_w[rl];
        atomicAdd(out + (size_t)s_tok[rl] * DDIM + d0 + n0w + nt * 16 + (lane & 15), v);
      }
    }
  }
}

// ---------------------------------------------------------------------------
extern "C" void kernel_launch(void* const* d_in, const int* in_sizes, int n_in,
                              void* d_out, int out_size, void* d_ws, size_t ws_size,
                              hipStream_t stream) {
  (void)in_sizes; (void)n_in; (void)ws_size;
  const float* x  = (const float*)d_in[0];
  const float* rw = (const float*)d_in[1];
  const float* wg = (const float*)d_in[2];
  const float* wu = (const float*)d_in[3];
  const float* wd = (const float*)d_in[4];
  float* out = (float*)d_out;

  // ws layout (bytes): needs ~56.3 MB
  char* ws = (char*)d_ws;
  unsigned short* xb  = (unsigned short*)(ws + 0);          // 16,777,216  [T][D] bf16
  unsigned short* wgt = (unsigned short*)(ws + 16777216);   //  8,388,608  [E][F][D]
  unsigned short* wut = (unsigned short*)(ws + 25165824);   //  8,388,608
  unsigned short* wdt = (unsigned short*)(ws + 33554432);   //  8,388,608  [E][D][F]
  unsigned short* hbuf= (unsigned short*)(ws + 41943040);   // 16,777,216  [2T][F]
  float* topkw = (float*)(ws + 58720256);                   // 65,536
  int*   topki = (int*)  (ws + 58785792);                   // 65,536
  int*   at    = (int*)  (ws + 58851328);                   // 65,536
  float* aw    = (float*)(ws + 58916864);                   // 65,536
  int*   ctrs  = (int*)  (ws + 58982400);                   // 256

  hipMemsetAsync(ctrs, 0, 256, stream);
  hipMemsetAsync(out, 0, (size_t)out_size * sizeof(float), stream);

  k_cvt_x<<<4096, 256, 0, stream>>>(x, xb);                       // T*D/8/256
  k_tcvt <<<dim3(16, 32, 8), 256, 0, stream>>>(wg, wgt, 1024, 512);
  k_tcvt <<<dim3(16, 32, 8), 256, 0, stream>>>(wu, wut, 1024, 512);
  k_tcvt <<<dim3(32, 16, 8), 256, 0, stream>>>(wd, wdt, 512, 1024);
  k_router<<<2048, 256, 0, stream>>>(x, rw, topki, topkw, ctrs);
  k_scan  <<<1, 64, 0, stream>>>(ctrs);
  k_scatter<<<32, 256, 0, stream>>>(topki, topkw, ctrs, at, aw);
  k_gateup<<<dim3(4, 512, 8), 256, 0, stream>>>(xb, wgt, wut, at, ctrs, hbuf);
  k_down  <<<dim3(8, 512, 8), 256, 0, stream>>>(hbuf, wdt, at, aw, ctrs, out);
}

// Round 2
// 379.630 us; speedup vs baseline: 1.6959x; 1.6959x over previous
//
#include <hip/hip_runtime.h>
#include <hip/hip_bf16.h>

// MoE top-2 router + grouped SwiGLU experts, MI355X gfx950.
// T=8192 tokens, D=1024, E=8, F=512, top-k=2. fp32 in/out, bf16 MFMA compute.

typedef __attribute__((ext_vector_type(4))) float  f32x4;
typedef __attribute__((ext_vector_type(8))) unsigned short us8;
typedef __attribute__((ext_vector_type(4))) unsigned short us4;
typedef __bf16 bf16_t;
typedef __attribute__((ext_vector_type(8))) bf16_t bf16x8;

#define TTOK 8192
#define DDIM 1024
#define EEXP 8
#define FDIM 512

__device__ __forceinline__ unsigned short f2bf(float f) {
  unsigned int u = __float_as_uint(f);
  u = (u + 0x7FFFu + ((u >> 16) & 1u)) >> 16;   // RNE
  return (unsigned short)u;
}

// ---------------- convert x fp32 -> bf16 (8 elems/thread) ----------------
__global__ __launch_bounds__(256) void k_cvt_x(const float* __restrict__ x,
                                               unsigned short* __restrict__ xb) {
  int i = blockIdx.x * 256 + threadIdx.x;            // grid sized exactly T*D/8
  const f32x4* s = (const f32x4*)x + (size_t)i * 2;
  f32x4 a = s[0], b = s[1];
  us8 o;
  o[0]=f2bf(a[0]); o[1]=f2bf(a[1]); o[2]=f2bf(a[2]); o[3]=f2bf(a[3]);
  o[4]=f2bf(b[0]); o[5]=f2bf(b[1]); o[6]=f2bf(b[2]); o[7]=f2bf(b[3]);
  *((us8*)xb + i) = o;
}

// ---- transpose+convert: src fp32 [e][M][N] -> dst bf16 [e][N][M] ----
__global__ __launch_bounds__(256) void k_tcvt(const float* __restrict__ src,
                                              unsigned short* __restrict__ dst,
                                              int M, int N) {
  __shared__ float tile[32][33];
  int e  = blockIdx.z;
  int m0 = blockIdx.y * 32, n0 = blockIdx.x * 32;
  const float* s = src + (size_t)e * M * N;
  unsigned short* d = dst + (size_t)e * M * N;
  int r  = threadIdx.x >> 3;
  int c4 = (threadIdx.x & 7) * 4;
  f32x4 v = *(const f32x4*)(s + (size_t)(m0 + r) * N + n0 + c4);
  tile[r][c4+0] = v[0]; tile[r][c4+1] = v[1];
  tile[r][c4+2] = v[2]; tile[r][c4+3] = v[3];
  __syncthreads();
  us4 o;
  o[0] = f2bf(tile[c4+0][r]); o[1] = f2bf(tile[c4+1][r]);
  o[2] = f2bf(tile[c4+2][r]); o[3] = f2bf(tile[c4+3][r]);
  *(us4*)(d + (size_t)(n0 + r) * M + m0 + c4) = o;
}

// ---------------- router: logits (fp64 lane-acc), top-2, renorm ------------
// LDS-staged router weight, no atomics, fp32 butterfly reduce.
__global__ __launch_bounds__(256) void k_router(const float* __restrict__ x,
                                                const float* __restrict__ rw,
                                                int* __restrict__ topki,
                                                float* __restrict__ topkw) {
  __shared__ float wlds[8 * 1024];                   // 32 KB fp32
  int tid = threadIdx.x;
  #pragma unroll
  for (int i = 0; i < 8; ++i)
    ((f32x4*)wlds)[tid + i * 256] = ((const f32x4*)rw)[tid + i * 256];
  __syncthreads();

  int wv = tid >> 6, lane = tid & 63;
  int t = blockIdx.x * 4 + wv;                       // grid 2048 -> 8192 tokens
  const f32x4* xr = (const f32x4*)(x + (size_t)t * DDIM);
  f32x4 xv[4];                                       // all loads in flight up-front
  #pragma unroll
  for (int j = 0; j < 4; ++j) xv[j] = xr[j * 64 + lane];   // coalesced 16B/lane
  double xd[16];
  #pragma unroll
  for (int j = 0; j < 4; ++j) {
    xd[j*4+0] = xv[j][0]; xd[j*4+1] = xv[j][1];
    xd[j*4+2] = xv[j][2]; xd[j*4+3] = xv[j][3];
  }
  float pf[8];
  #pragma unroll
  for (int e = 0; e < 8; ++e) {
    double acc = 0.0;
    #pragma unroll
    for (int j = 0; j < 4; ++j) {
      f32x4 wv4 = ((const f32x4*)(wlds + e * 1024))[j * 64 + lane];
      acc = fma((double)wv4[0], xd[j*4+0], acc);
      acc = fma((double)wv4[1], xd[j*4+1], acc);
      acc = fma((double)wv4[2], xd[j*4+2], acc);
      acc = fma((double)wv4[3], xd[j*4+3], acc);
    }
    pf[e] = (float)acc;
  }
  #pragma unroll
  for (int e = 0; e < 8; ++e) {
    #pragma unroll
    for (int off = 32; off >= 1; off >>= 1)
      pf[e] += __shfl_xor(pf[e], off, 64);
  }
  if (lane == 0) {
    int i1 = 0;
    #pragma unroll
    for (int e2 = 1; e2 < 8; ++e2) if (pf[e2] > pf[i1]) i1 = e2;
    int i2 = (i1 == 0) ? 1 : 0;
    #pragma unroll
    for (int e2 = 0; e2 < 8; ++e2) if (e2 != i1 && pf[e2] > pf[i2]) i2 = e2;
    // renormalized top-2 of softmax == softmax over the 2 selected logits
    float d21 = pf[i2] - pf[i1];
    float e1  = __expf(d21);
    float s   = 1.f + e1;
    topki[2*t]   = i1;       topki[2*t+1] = i2;
    topkw[2*t]   = 1.f / s;  topkw[2*t+1] = e1 / s;
  }
}

// -------- histogram of expert assignments (LDS-aggregated) -----------------
__global__ __launch_bounds__(256) void k_count(const int* __restrict__ topki,
                                               int* __restrict__ ctrs) {
  __shared__ int h[8];
  if (threadIdx.x < 8) h[threadIdx.x] = 0;
  __syncthreads();
  int i = blockIdx.x * 256 + threadIdx.x;            // grid 64 -> 16384 entries
  atomicAdd(&h[topki[i]], 1);
  __syncthreads();
  if (threadIdx.x < 8) atomicAdd(&ctrs[threadIdx.x], h[threadIdx.x]);
}

// ctrs layout (ints): [0..7]=counts  [8..16]=offsets  [17..24]=pos
__global__ void k_scan(int* __restrict__ ctrs) {
  if (threadIdx.x == 0 && blockIdx.x == 0) {
    ctrs[8] = 0;
    #pragma unroll
    for (int e = 0; e < 8; ++e) ctrs[9 + e] = ctrs[8 + e] + ctrs[e];
    #pragma unroll
    for (int e = 0; e < 8; ++e) ctrs[17 + e] = 0;
  }
}

// -------- scatter with block-aggregated reservations -----------------------
__global__ __launch_bounds__(256) void k_scatter(const int* __restrict__ topki,
                                                 const float* __restrict__ topkw,
                                                 int* __restrict__ ctrs,
                                                 int* __restrict__ at,
                                                 float* __restrict__ aw) {
  __shared__ int lc[8], base[8];
  int tid = threadIdx.x;
  if (tid < 8) lc[tid] = 0;
  __syncthreads();
  int t = blockIdx.x * 256 + tid;                    // grid 32
  int e0 = topki[2*t], e1 = topki[2*t+1];
  int r0 = atomicAdd(&lc[e0], 1);                    // LDS-local rank
  int r1 = atomicAdd(&lc[e1], 1);
  __syncthreads();
  if (tid < 8) base[tid] = atomicAdd(&ctrs[17 + tid], lc[tid]);  // 8 global/block
  __syncthreads();
  int a0 = ctrs[8 + e0] + base[e0] + r0;
  int a1 = ctrs[8 + e1] + base[e1] + r1;
  at[a0] = t; aw[a0] = topkw[2*t];
  at[a1] = t; aw[a1] = topkw[2*t+1];
}

// -------- grouped GEMM 1: h = silu(x@wg) * (x@wu), per-expert segments -----
// tile 32(rows) x 128(f), BK=64, MFMA 16x16x32 bf16, XOR-swizzled LDS.
__global__ __launch_bounds__(256) void k_gateup(
    const unsigned short* __restrict__ xb,   // [T][D] bf16
    const unsigned short* __restrict__ wgt,  // [E][F][D] bf16 (transposed)
    const unsigned short* __restrict__ wut,  // [E][F][D]
    const int* __restrict__ at,
    const int* __restrict__ ctrs,
    unsigned short* __restrict__ h) {        // [2T][F] bf16
  int e    = blockIdx.z;
  int seg0 = ctrs[8 + e];
  int cnt  = ctrs[9 + e] - seg0;
  int row0 = blockIdx.y * 32;
  if (row0 >= cnt) return;                   // early-exit inactive tiles
  int f0 = blockIdx.x * 128;

  __shared__ unsigned short lA [32 * 64];    // [row][k], 16B-unit XOR swizzle
  __shared__ unsigned short lBg[128 * 64];   // [n][k]
  __shared__ unsigned short lBu[128 * 64];

  int tid = threadIdx.x;
  int arow = tid >> 3, aunit = tid & 7;
  int rg   = row0 + arow;
  int tokA = at[seg0 + ((rg < cnt) ? rg : 0)];     // dummy = segment row 0
  const unsigned short* srcA = xb + (size_t)tokA * DDIM + aunit * 8;
  int laOff = (arow * 8 + (aunit ^ (arow & 7))) * 8;

  int w = tid >> 6, lane = tid & 63;
  int m0w = (w & 1) * 16, n0w = (w >> 1) * 64;

  f32x4 zero = {0.f, 0.f, 0.f, 0.f};
  f32x4 accg[4], accu[4];
  #pragma unroll
  for (int nt = 0; nt < 4; ++nt) { accg[nt] = zero; accu[nt] = zero; }

  const unsigned short* bgBase = wgt + ((size_t)e * FDIM + f0) * DDIM;
  const unsigned short* buBase = wut + ((size_t)e * FDIM + f0) * DDIM;

  for (int ks = 0; ks < DDIM / 64; ++ks) {
    int k0 = ks * 64;
    *(us8*)&lA[laOff] = *(const us8*)(srcA + k0);
    #pragma unroll
    for (int i = 0; i < 4; ++i) {
      int lin = tid + i * 256;
      int br = lin >> 3, bu = lin & 7;
      int off = (br * 8 + (bu ^ (br & 7))) * 8;
      size_t goff = (size_t)br * DDIM + k0 + bu * 8;
      *(us8*)&lBg[off] = *(const us8*)(bgBase + goff);
      *(us8*)&lBu[off] = *(const us8*)(buBase + goff);
    }
    __syncthreads();
    #pragma unroll
    for (int kk = 0; kk < 2; ++kk) {
      int ar = m0w + (lane & 15);
      int au = (kk * 4 + (lane >> 4)) ^ (ar & 7);
      bf16x8 af = *(const bf16x8*)&lA[(ar * 8 + au) * 8];
      #pragma unroll
      for (int nt = 0; nt < 4; ++nt) {
        int br = n0w + nt * 16 + (lane & 15);
        int bu = (kk * 4 + (lane >> 4)) ^ (br & 7);
        bf16x8 bg  = *(const bf16x8*)&lBg[(br * 8 + bu) * 8];
        bf16x8 buf = *(const bf16x8*)&lBu[(br * 8 + bu) * 8];
        accg[nt] = __builtin_amdgcn_mfma_f32_16x16x32_bf16(af, bg,  accg[nt], 0, 0, 0);
        accu[nt] = __builtin_amdgcn_mfma_f32_16x16x32_bf16(af, buf, accu[nt], 0, 0, 0);
      }
    }
    __syncthreads();
  }
  // epilogue: silu(g)*u -> h (C layout: col=lane&15, row=(lane>>4)*4+j)
  #pragma unroll
  for (int nt = 0; nt < 4; ++nt) {
    #pragma unroll
    for (int j = 0; j < 4; ++j) {
      int rl = m0w + (lane >> 4) * 4 + j;
      if (row0 + rl < cnt) {
        float g = accg[nt][j], u = accu[nt][j];
        float hv = g * (1.f / (1.f + __expf(-g))) * u;
        h[(size_t)(seg0 + row0 + rl) * FDIM + f0 + n0w + nt * 16 + (lane & 15)] = f2bf(hv);
      }
    }
  }
}

// -------- grouped GEMM 2: out[tok] += w * (h @ w_down[e]) ------------------
__global__ __launch_bounds__(256) void k_down(
    const unsigned short* __restrict__ h,    // [2T][F] bf16
    const unsigned short* __restrict__ wdt,  // [E][D][F] bf16 (transposed)
    const int* __restrict__ at,
    const float* __restrict__ aw,
    const int* __restrict__ ctrs,
    float* __restrict__ out) {               // [T][D] fp32 (zeroed)
  int e    = blockIdx.z;
  int seg0 = ctrs[8 + e];
  int cnt  = ctrs[9 + e] - seg0;
  int row0 = blockIdx.y * 32;
  if (row0 >= cnt) return;
  int d0 = blockIdx.x * 128;

  __shared__ unsigned short lA[32 * 64];
  __shared__ unsigned short lB[128 * 64];
  __shared__ int   s_tok[32];
  __shared__ float s_w[32];

  int tid = threadIdx.x;
  if (tid < 32) {
    int rg = row0 + tid;
    int a  = seg0 + ((rg < cnt) ? rg : 0);
    s_tok[tid] = at[a];
    s_w[tid]   = aw[a];
  }
  int arow = tid >> 3, aunit = tid & 7;
  int rg = row0 + arow;
  const unsigned short* srcA = h + (size_t)(seg0 + ((rg < cnt) ? rg : 0)) * FDIM + aunit * 8;
  int laOff = (arow * 8 + (aunit ^ (arow & 7))) * 8;

  int w = tid >> 6, lane = tid & 63;
  int m0w = (w & 1) * 16, n0w = (w >> 1) * 64;

  f32x4 zero = {0.f, 0.f, 0.f, 0.f};
  f32x4 acc[4];
  #pragma unroll
  for (int nt = 0; nt < 4; ++nt) acc[nt] = zero;

  const unsigned short* bBase = wdt + ((size_t)e * DDIM + d0) * FDIM;

  for (int ks = 0; ks < FDIM / 64; ++ks) {
    int k0 = ks * 64;
    *(us8*)&lA[laOff] = *(const us8*)(srcA + k0);
    #pragma unroll
    for (int i = 0; i < 4; ++i) {
      int lin = tid + i * 256;
      int br = lin >> 3, bu = lin & 7;
      int off = (br * 8 + (bu ^ (br & 7))) * 8;
      *(us8*)&lB[off] = *(const us8*)(bBase + (size_t)br * FDIM + k0 + bu * 8);
    }
    __syncthreads();
    #pragma unroll
    for (int kk = 0; kk < 2; ++kk) {
      int ar = m0w + (lane & 15);
      int au = (kk * 4 + (lane >> 4)) ^ (ar & 7);
      bf16x8 af = *(const bf16x8*)&lA[(ar * 8 + au) * 8];
      #pragma unroll
      for (int nt = 0; nt < 4; ++nt) {
        int br = n0w + nt * 16 + (lane & 15);
        int bu = (kk * 4 + (lane >> 4)) ^ (br & 7);
        bf16x8 bf = *(const bf16x8*)&lB[(br * 8 + bu) * 8];
        acc[nt] = __builtin_amdgcn_mfma_f32_16x16x32_bf16(af, bf, acc[nt], 0, 0, 0);
      }
    }
    __syncthreads();
  }
  #pragma unroll
  for (int nt = 0; nt < 4; ++nt) {
    #pragma unroll
    for (int j = 0; j < 4; ++j) {
      int rl = m0w + (lane >> 4) * 4 + j;
      if (row0 + rl < cnt) {
        float v = acc[nt][j] * s_w[rl];
        atomicAdd(out + (size_t)s_tok[rl] * DDIM + d0 + n0w + nt * 16 + (lane & 15), v);
      }
    }
  }
}

// ---------------------------------------------------------------------------
extern "C" void kernel_launch(void* const* d_in, const int* in_sizes, int n_in,
                              void* d_out, int out_size, void* d_ws, size_t ws_size,
                              hipStream_t stream) {
  (void)in_sizes; (void)n_in; (void)ws_size;
  const float* x  = (const float*)d_in[0];
  const float* rw = (const float*)d_in[1];
  const float* wg = (const float*)d_in[2];
  const float* wu = (const float*)d_in[3];
  const float* wd = (const float*)d_in[4];
  float* out = (float*)d_out;

  // ws layout (bytes): needs ~59 MB
  char* ws = (char*)d_ws;
  unsigned short* xb  = (unsigned short*)(ws + 0);          // 16,777,216  [T][D] bf16
  unsigned short* wgt = (unsigned short*)(ws + 16777216);   //  8,388,608  [E][F][D]
  unsigned short* wut = (unsigned short*)(ws + 25165824);   //  8,388,608
  unsigned short* wdt = (unsigned short*)(ws + 33554432);   //  8,388,608  [E][D][F]
  unsigned short* hbuf= (unsigned short*)(ws + 41943040);   // 16,777,216  [2T][F]
  float* topkw = (float*)(ws + 58720256);                   // 65,536
  int*   topki = (int*)  (ws + 58785792);                   // 65,536
  int*   at    = (int*)  (ws + 58851328);                   // 65,536
  float* aw    = (float*)(ws + 58916864);                   // 65,536
  int*   ctrs  = (int*)  (ws + 58982400);                   // 256

  hipMemsetAsync(ctrs, 0, 256, stream);
  hipMemsetAsync(out, 0, (size_t)out_size * sizeof(float), stream);

  k_cvt_x<<<4096, 256, 0, stream>>>(x, xb);                       // T*D/8/256
  k_tcvt <<<dim3(16, 32, 8), 256, 0, stream>>>(wg, wgt, 1024, 512);
  k_tcvt <<<dim3(16, 32, 8), 256, 0, stream>>>(wu, wut, 1024, 512);
  k_tcvt <<<dim3(32, 16, 8), 256, 0, stream>>>(wd, wdt, 512, 1024);
  k_router<<<2048, 256, 0, stream>>>(x, rw, topki, topkw);
  k_count <<<64, 256, 0, stream>>>(topki, ctrs);
  k_scan  <<<1, 64, 0, stream>>>(ctrs);
  k_scatter<<<32, 256, 0, stream>>>(topki, topkw, ctrs, at, aw);
  k_gateup<<<dim3(4, 512, 8), 256, 0, stream>>>(xb, wgt, wut, at, ctrs, hbuf);
  k_down  <<<dim3(8, 512, 8), 256, 0, stream>>>(hbuf, wdt, at, aw, ctrs, out);
}

// Round 3
// 323.667 us; speedup vs baseline: 1.9891x; 1.1729x over previous
//
#include <hip/hip_runtime.h>
#include <hip/hip_bf16.h>

// MoE top-2 router + grouped SwiGLU experts, MI355X gfx950.
// T=8192 tokens, D=1024, E=8, F=512, top-k=2. fp32 in/out, bf16 MFMA compute.

typedef __attribute__((ext_vector_type(4))) float  f32x4;
typedef __attribute__((ext_vector_type(8))) unsigned short us8;
typedef __attribute__((ext_vector_type(4))) unsigned short us4;
typedef __bf16 bf16_t;
typedef __attribute__((ext_vector_type(8))) bf16_t bf16x8;

#define TTOK 8192
#define DDIM 1024
#define EEXP 8
#define FDIM 512

__device__ __forceinline__ unsigned short f2bf(float f) {
  unsigned int u = __float_as_uint(f);
  u = (u + 0x7FFFu + ((u >> 16) & 1u)) >> 16;   // RNE
  return (unsigned short)u;
}

__device__ __forceinline__ void gload16(const void* g, void* l) {
  __builtin_amdgcn_global_load_lds(
      (const __attribute__((address_space(1))) void*)g,
      (__attribute__((address_space(3))) void*)l, 16, 0, 0);
}

// ---------------- convert x fp32 -> bf16 (8 elems/thread) ----------------
__global__ __launch_bounds__(256) void k_cvt_x(const float* __restrict__ x,
                                               unsigned short* __restrict__ xb) {
  int i = blockIdx.x * 256 + threadIdx.x;            // grid sized exactly T*D/8
  const f32x4* s = (const f32x4*)x + (size_t)i * 2;
  f32x4 a = s[0], b = s[1];
  us8 o;
  o[0]=f2bf(a[0]); o[1]=f2bf(a[1]); o[2]=f2bf(a[2]); o[3]=f2bf(a[3]);
  o[4]=f2bf(b[0]); o[5]=f2bf(b[1]); o[6]=f2bf(b[2]); o[7]=f2bf(b[3]);
  *((us8*)xb + i) = o;
}

// ---- transpose+convert: src fp32 [e][M][N] -> dst bf16 [e][N][M] ----
__global__ __launch_bounds__(256) void k_tcvt(const float* __restrict__ src,
                                              unsigned short* __restrict__ dst,
                                              int M, int N) {
  __shared__ float tile[32][33];
  int e  = blockIdx.z;
  int m0 = blockIdx.y * 32, n0 = blockIdx.x * 32;
  const float* s = src + (size_t)e * M * N;
  unsigned short* d = dst + (size_t)e * M * N;
  int r  = threadIdx.x >> 3;
  int c4 = (threadIdx.x & 7) * 4;
  f32x4 v = *(const f32x4*)(s + (size_t)(m0 + r) * N + n0 + c4);
  tile[r][c4+0] = v[0]; tile[r][c4+1] = v[1];
  tile[r][c4+2] = v[2]; tile[r][c4+3] = v[3];
  __syncthreads();
  us4 o;
  o[0] = f2bf(tile[c4+0][r]); o[1] = f2bf(tile[c4+1][r]);
  o[2] = f2bf(tile[c4+2][r]); o[3] = f2bf(tile[c4+3][r]);
  *(us4*)(d + (size_t)(n0 + r) * M + m0 + c4) = o;
}

// ---------------- router: logits (fp64 lane-acc), top-2, renorm ------------
__global__ __launch_bounds__(256) void k_router(const float* __restrict__ x,
                                                const float* __restrict__ rw,
                                                int* __restrict__ topki,
                                                float* __restrict__ topkw) {
  __shared__ float wlds[8 * 1024];                   // 32 KB fp32
  int tid = threadIdx.x;
  #pragma unroll
  for (int i = 0; i < 8; ++i)
    ((f32x4*)wlds)[tid + i * 256] = ((const f32x4*)rw)[tid + i * 256];
  __syncthreads();

  int wv = tid >> 6, lane = tid & 63;
  int t = blockIdx.x * 4 + wv;                       // grid 2048 -> 8192 tokens
  const f32x4* xr = (const f32x4*)(x + (size_t)t * DDIM);
  f32x4 xv[4];
  #pragma unroll
  for (int j = 0; j < 4; ++j) xv[j] = xr[j * 64 + lane];   // coalesced 16B/lane
  double xd[16];
  #pragma unroll
  for (int j = 0; j < 4; ++j) {
    xd[j*4+0] = xv[j][0]; xd[j*4+1] = xv[j][1];
    xd[j*4+2] = xv[j][2]; xd[j*4+3] = xv[j][3];
  }
  float pf[8];
  #pragma unroll
  for (int e = 0; e < 8; ++e) {
    double acc = 0.0;
    #pragma unroll
    for (int j = 0; j < 4; ++j) {
      f32x4 wv4 = ((const f32x4*)(wlds + e * 1024))[j * 64 + lane];
      acc = fma((double)wv4[0], xd[j*4+0], acc);
      acc = fma((double)wv4[1], xd[j*4+1], acc);
      acc = fma((double)wv4[2], xd[j*4+2], acc);
      acc = fma((double)wv4[3], xd[j*4+3], acc);
    }
    pf[e] = (float)acc;
  }
  #pragma unroll
  for (int e = 0; e < 8; ++e) {
    #pragma unroll
    for (int off = 32; off >= 1; off >>= 1)
      pf[e] += __shfl_xor(pf[e], off, 64);
  }
  if (lane == 0) {
    int i1 = 0;
    #pragma unroll
    for (int e2 = 1; e2 < 8; ++e2) if (pf[e2] > pf[i1]) i1 = e2;
    int i2 = (i1 == 0) ? 1 : 0;
    #pragma unroll
    for (int e2 = 0; e2 < 8; ++e2) if (e2 != i1 && pf[e2] > pf[i2]) i2 = e2;
    float d21 = pf[i2] - pf[i1];
    float e1  = __expf(d21);
    float s   = 1.f + e1;
    topki[2*t]   = i1;       topki[2*t+1] = i2;
    topkw[2*t]   = 1.f / s;  topkw[2*t+1] = e1 / s;
  }
}

// -------- histogram of expert assignments (LDS-aggregated) -----------------
__global__ __launch_bounds__(256) void k_count(const int* __restrict__ topki,
                                               int* __restrict__ ctrs) {
  __shared__ int h[8];
  if (threadIdx.x < 8) h[threadIdx.x] = 0;
  __syncthreads();
  int i = blockIdx.x * 256 + threadIdx.x;            // grid 64 -> 16384 entries
  atomicAdd(&h[topki[i]], 1);
  __syncthreads();
  if (threadIdx.x < 8) atomicAdd(&ctrs[threadIdx.x], h[threadIdx.x]);
}

// ctrs layout (ints): [0..7]=counts  [8..16]=offsets  [17..24]=pos
__global__ void k_scan(int* __restrict__ ctrs) {
  if (threadIdx.x == 0 && blockIdx.x == 0) {
    ctrs[8] = 0;
    #pragma unroll
    for (int e = 0; e < 8; ++e) ctrs[9 + e] = ctrs[8 + e] + ctrs[e];
    #pragma unroll
    for (int e = 0; e < 8; ++e) ctrs[17 + e] = 0;
  }
}

// -------- scatter with block-aggregated reservations -----------------------
__global__ __launch_bounds__(256) void k_scatter(const int* __restrict__ topki,
                                                 const float* __restrict__ topkw,
                                                 int* __restrict__ ctrs,
                                                 int* __restrict__ at,
                                                 float* __restrict__ aw) {
  __shared__ int lc[8], base[8];
  int tid = threadIdx.x;
  if (tid < 8) lc[tid] = 0;
  __syncthreads();
  int t = blockIdx.x * 256 + tid;                    // grid 32
  int e0 = topki[2*t], e1 = topki[2*t+1];
  int r0 = atomicAdd(&lc[e0], 1);
  int r1 = atomicAdd(&lc[e1], 1);
  __syncthreads();
  if (tid < 8) base[tid] = atomicAdd(&ctrs[17 + tid], lc[tid]);
  __syncthreads();
  int a0 = ctrs[8 + e0] + base[e0] + r0;
  int a1 = ctrs[8 + e1] + base[e1] + r1;
  at[a0] = t; aw[a0] = topkw[2*t];
  at[a1] = t; aw[a1] = topkw[2*t+1];
}

// -------- grouped GEMM 1: h = silu(x@wg) * (x@wu) --------------------------
// 128x128 tile, BK=64, 4 waves @64x64 (4x4 frags), global_load_lds(16B)
// staging with pre-swizzled source, XOR-swizzled ds_read_b128.
__global__ __launch_bounds__(256) void k_gateup(
    const unsigned short* __restrict__ xb,   // [T][D] bf16
    const unsigned short* __restrict__ wgt,  // [E][F][D] bf16 (transposed)
    const unsigned short* __restrict__ wut,  // [E][F][D]
    const int* __restrict__ at,
    const int* __restrict__ ctrs,
    unsigned short* __restrict__ h) {        // [2T][F] bf16
  int e    = blockIdx.z;
  int seg0 = ctrs[8 + e];
  int cnt  = ctrs[9 + e] - seg0;
  int row0 = blockIdx.y * 128;
  if (row0 >= cnt) return;                   // early-exit inactive tiles
  int f0 = blockIdx.x * 128;

  __shared__ unsigned short lA [128 * 64];   // 16 KB, linear (gload_lds dest)
  __shared__ unsigned short lBg[128 * 64];
  __shared__ unsigned short lBu[128 * 64];
  __shared__ int s_tok[128];

  int tid = threadIdx.x;
  if (tid < 128) {
    int rg = row0 + tid;
    s_tok[tid] = at[seg0 + ((rg < cnt) ? rg : 0)];  // clamp ragged tail
  }
  __syncthreads();

  // staging geometry: round i covers rows i*32+(tid>>3), unit tid&7.
  // LDS slot lin=i*256+tid holds global unit (u ^ (row&7))  [involution]
  int a_row[4], a_su[4];
  const unsigned short* aSrc[4];
  size_t bOff[4];
  #pragma unroll
  for (int i = 0; i < 4; ++i) {
    a_row[i] = i * 32 + (tid >> 3);
    a_su[i]  = (tid & 7) ^ (a_row[i] & 7);
    aSrc[i]  = xb + (size_t)s_tok[a_row[i]] * DDIM + a_su[i] * 8;
    bOff[i]  = (size_t)a_row[i] * DDIM + a_su[i] * 8;
  }
  const unsigned short* bgBase = wgt + ((size_t)e * FDIM + f0) * DDIM;
  const unsigned short* buBase = wut + ((size_t)e * FDIM + f0) * DDIM;

  int w = tid >> 6, lane = tid & 63;
  int wr = (w >> 1) * 64, wc = (w & 1) * 64;       // wave quadrant

  f32x4 zero = {0.f, 0.f, 0.f, 0.f};
  f32x4 accg[4][4], accu[4][4];
  #pragma unroll
  for (int mt = 0; mt < 4; ++mt)
    #pragma unroll
    for (int nt = 0; nt < 4; ++nt) { accg[mt][nt] = zero; accu[mt][nt] = zero; }

  for (int ks = 0; ks < DDIM / 64; ++ks) {
    int k0 = ks * 64;
    #pragma unroll
    for (int i = 0; i < 4; ++i) {
      int dst = (i * 256 + tid) * 8;
      gload16(aSrc[i] + k0,          &lA [dst]);
      gload16(bgBase + bOff[i] + k0, &lBg[dst]);
      gload16(buBase + bOff[i] + k0, &lBu[dst]);
    }
    __syncthreads();                              // drains vmcnt before use
    #pragma unroll
    for (int kk = 0; kk < 2; ++kk) {
      bf16x8 af[4];
      #pragma unroll
      for (int mt = 0; mt < 4; ++mt) {
        int ar = wr + mt * 16 + (lane & 15);
        int au = (kk * 4 + (lane >> 4)) ^ (ar & 7);
        af[mt] = *(const bf16x8*)&lA[(ar * 8 + au) * 8];
      }
      #pragma unroll
      for (int nt = 0; nt < 4; ++nt) {
        int br = wc + nt * 16 + (lane & 15);
        int bu = (kk * 4 + (lane >> 4)) ^ (br & 7);
        bf16x8 bg = *(const bf16x8*)&lBg[(br * 8 + bu) * 8];
        bf16x8 bv = *(const bf16x8*)&lBu[(br * 8 + bu) * 8];
        #pragma unroll
        for (int mt = 0; mt < 4; ++mt) {
          accg[mt][nt] = __builtin_amdgcn_mfma_f32_16x16x32_bf16(af[mt], bg, accg[mt][nt], 0, 0, 0);
          accu[mt][nt] = __builtin_amdgcn_mfma_f32_16x16x32_bf16(af[mt], bv, accu[mt][nt], 0, 0, 0);
        }
      }
    }
    __syncthreads();
  }
  // epilogue: silu(g)*u -> h  (C layout: col=lane&15, row=(lane>>4)*4+j)
  #pragma unroll
  for (int mt = 0; mt < 4; ++mt) {
    #pragma unroll
    for (int nt = 0; nt < 4; ++nt) {
      #pragma unroll
      for (int j = 0; j < 4; ++j) {
        int rl = wr + mt * 16 + (lane >> 4) * 4 + j;
        if (row0 + rl < cnt) {
          float g = accg[mt][nt][j], u = accu[mt][nt][j];
          float hv = g * (1.f / (1.f + __expf(-g))) * u;
          h[(size_t)(seg0 + row0 + rl) * FDIM + f0 + wc + nt * 16 + (lane & 15)] = f2bf(hv);
        }
      }
    }
  }
}

// -------- grouped GEMM 2: out[tok] += w * (h @ w_down[e]) ------------------
// same 128x128 structure; A (=h) is segment-contiguous, no gather.
__global__ __launch_bounds__(256) void k_down(
    const unsigned short* __restrict__ h,    // [2T][F] bf16
    const unsigned short* __restrict__ wdt,  // [E][D][F] bf16 (transposed)
    const int* __restrict__ at,
    const float* __restrict__ aw,
    const int* __restrict__ ctrs,
    float* __restrict__ out) {               // [T][D] fp32 (zeroed)
  int e    = blockIdx.z;
  int seg0 = ctrs[8 + e];
  int cnt  = ctrs[9 + e] - seg0;
  int row0 = blockIdx.y * 128;
  if (row0 >= cnt) return;
  int d0 = blockIdx.x * 128;

  __shared__ unsigned short lA[128 * 64];    // 16 KB
  __shared__ unsigned short lB[128 * 64];
  __shared__ int   s_tok[128];
  __shared__ float s_w[128];

  int tid = threadIdx.x;
  if (tid < 128) {
    int rg = row0 + tid;
    int a  = seg0 + ((rg < cnt) ? rg : 0);
    s_tok[tid] = at[a];
    s_w[tid]   = aw[a];
  }

  int a_row[4], a_su[4];
  const unsigned short* aSrc[4];
  size_t bOff[4];
  #pragma unroll
  for (int i = 0; i < 4; ++i) {
    a_row[i] = i * 32 + (tid >> 3);
    a_su[i]  = (tid & 7) ^ (a_row[i] & 7);
    int rr   = (row0 + a_row[i] < cnt) ? row0 + a_row[i] : 0;   // clamp (OOB!)
    aSrc[i]  = h + (size_t)(seg0 + rr) * FDIM + a_su[i] * 8;
    bOff[i]  = (size_t)a_row[i] * FDIM + a_su[i] * 8;
  }
  const unsigned short* bBase = wdt + ((size_t)e * DDIM + d0) * FDIM;

  int w = tid >> 6, lane = tid & 63;
  int wr = (w >> 1) * 64, wc = (w & 1) * 64;

  f32x4 zero = {0.f, 0.f, 0.f, 0.f};
  f32x4 acc[4][4];
  #pragma unroll
  for (int mt = 0; mt < 4; ++mt)
    #pragma unroll
    for (int nt = 0; nt < 4; ++nt) acc[mt][nt] = zero;

  for (int ks = 0; ks < FDIM / 64; ++ks) {
    int k0 = ks * 64;
    #pragma unroll
    for (int i = 0; i < 4; ++i) {
      int dst = (i * 256 + tid) * 8;
      gload16(aSrc[i] + k0,         &lA[dst]);
      gload16(bBase + bOff[i] + k0, &lB[dst]);
    }
    __syncthreads();
    #pragma unroll
    for (int kk = 0; kk < 2; ++kk) {
      bf16x8 af[4];
      #pragma unroll
      for (int mt = 0; mt < 4; ++mt) {
        int ar = wr + mt * 16 + (lane & 15);
        int au = (kk * 4 + (lane >> 4)) ^ (ar & 7);
        af[mt] = *(const bf16x8*)&lA[(ar * 8 + au) * 8];
      }
      #pragma unroll
      for (int nt = 0; nt < 4; ++nt) {
        int br = wc + nt * 16 + (lane & 15);
        int bu = (kk * 4 + (lane >> 4)) ^ (br & 7);
        bf16x8 bf = *(const bf16x8*)&lB[(br * 8 + bu) * 8];
        #pragma unroll
        for (int mt = 0; mt < 4; ++mt)
          acc[mt][nt] = __builtin_amdgcn_mfma_f32_16x16x32_bf16(af[mt], bf, acc[mt][nt], 0, 0, 0);
      }
    }
    __syncthreads();
  }
  #pragma unroll
  for (int mt = 0; mt < 4; ++mt) {
    #pragma unroll
    for (int nt = 0; nt < 4; ++nt) {
      #pragma unroll
      for (int j = 0; j < 4; ++j) {
        int rl = wr + mt * 16 + (lane >> 4) * 4 + j;
        if (row0 + rl < cnt) {
          float v = acc[mt][nt][j] * s_w[rl];
          atomicAdd(out + (size_t)s_tok[rl] * DDIM + d0 + wc + nt * 16 + (lane & 15), v);
        }
      }
    }
  }
}

// ---------------------------------------------------------------------------
extern "C" void kernel_launch(void* const* d_in, const int* in_sizes, int n_in,
                              void* d_out, int out_size, void* d_ws, size_t ws_size,
                              hipStream_t stream) {
  (void)in_sizes; (void)n_in; (void)ws_size;
  const float* x  = (const float*)d_in[0];
  const float* rw = (const float*)d_in[1];
  const float* wg = (const float*)d_in[2];
  const float* wu = (const float*)d_in[3];
  const float* wd = (const float*)d_in[4];
  float* out = (float*)d_out;

  // ws layout (bytes): ~59 MB
  char* ws = (char*)d_ws;
  unsigned short* xb  = (unsigned short*)(ws + 0);          // 16,777,216  [T][D] bf16
  unsigned short* wgt = (unsigned short*)(ws + 16777216);   //  8,388,608  [E][F][D]
  unsigned short* wut = (unsigned short*)(ws + 25165824);   //  8,388,608
  unsigned short* wdt = (unsigned short*)(ws + 33554432);   //  8,388,608  [E][D][F]
  unsigned short* hbuf= (unsigned short*)(ws + 41943040);   // 16,777,216  [2T][F]
  float* topkw = (float*)(ws + 58720256);                   // 65,536
  int*   topki = (int*)  (ws + 58785792);                   // 65,536
  int*   at    = (int*)  (ws + 58851328);                   // 65,536
  float* aw    = (float*)(ws + 58916864);                   // 65,536
  int*   ctrs  = (int*)  (ws + 58982400);                   // 256

  hipMemsetAsync(ctrs, 0, 256, stream);
  hipMemsetAsync(out, 0, (size_t)out_size * sizeof(float), stream);

  k_cvt_x<<<4096, 256, 0, stream>>>(x, xb);
  k_tcvt <<<dim3(16, 32, 8), 256, 0, stream>>>(wg, wgt, 1024, 512);
  k_tcvt <<<dim3(16, 32, 8), 256, 0, stream>>>(wu, wut, 1024, 512);
  k_tcvt <<<dim3(32, 16, 8), 256, 0, stream>>>(wd, wdt, 512, 1024);
  k_router<<<2048, 256, 0, stream>>>(x, rw, topki, topkw);
  k_count <<<64, 256, 0, stream>>>(topki, ctrs);
  k_scan  <<<1, 64, 0, stream>>>(ctrs);
  k_scatter<<<32, 256, 0, stream>>>(topki, topkw, ctrs, at, aw);
  k_gateup<<<dim3(4, 128, 8), 256, 0, stream>>>(xb, wgt, wut, at, ctrs, hbuf);
  k_down  <<<dim3(8, 128, 8), 256, 0, stream>>>(hbuf, wdt, at, aw, ctrs, out);
}

// Round 4
// 306.215 us; speedup vs baseline: 2.1025x; 1.0570x over previous
//
#include <hip/hip_runtime.h>
#include <hip/hip_bf16.h>

// MoE top-2 router + grouped SwiGLU experts, MI355X gfx950.
// T=8192 tokens, D=1024, E=8, F=512, top-k=2. fp32 in/out, bf16 MFMA compute.

typedef __attribute__((ext_vector_type(4))) float  f32x4;
typedef __attribute__((ext_vector_type(8))) unsigned short us8;
typedef __attribute__((ext_vector_type(4))) unsigned short us4;
typedef __bf16 bf16_t;
typedef __attribute__((ext_vector_type(8))) bf16_t bf16x8;

#define TTOK 8192
#define DDIM 1024
#define EEXP 8
#define FDIM 512

__device__ __forceinline__ unsigned short f2bf(float f) {
  unsigned int u = __float_as_uint(f);
  u = (u + 0x7FFFu + ((u >> 16) & 1u)) >> 16;   // RNE
  return (unsigned short)u;
}

__device__ __forceinline__ void gload16(const void* g, void* l) {
  __builtin_amdgcn_global_load_lds(
      (const __attribute__((address_space(1))) void*)g,
      (__attribute__((address_space(3))) void*)l, 16, 0, 0);
}

// ---------------- convert x fp32 -> bf16 (8 elems/thread) ----------------
__global__ __launch_bounds__(256) void k_cvt_x(const float* __restrict__ x,
                                               unsigned short* __restrict__ xb) {
  int i = blockIdx.x * 256 + threadIdx.x;
  const f32x4* s = (const f32x4*)x + (size_t)i * 2;
  f32x4 a = s[0], b = s[1];
  us8 o;
  o[0]=f2bf(a[0]); o[1]=f2bf(a[1]); o[2]=f2bf(a[2]); o[3]=f2bf(a[3]);
  o[4]=f2bf(b[0]); o[5]=f2bf(b[1]); o[6]=f2bf(b[2]); o[7]=f2bf(b[3]);
  *((us8*)xb + i) = o;
}

// ---- transpose+convert: src fp32 [e][M][N] -> dst bf16 [e][N][M] ----
__global__ __launch_bounds__(256) void k_tcvt(const float* __restrict__ src,
                                              unsigned short* __restrict__ dst,
                                              int M, int N) {
  __shared__ float tile[32][33];
  int e  = blockIdx.z;
  int m0 = blockIdx.y * 32, n0 = blockIdx.x * 32;
  const float* s = src + (size_t)e * M * N;
  unsigned short* d = dst + (size_t)e * M * N;
  int r  = threadIdx.x >> 3;
  int c4 = (threadIdx.x & 7) * 4;
  f32x4 v = *(const f32x4*)(s + (size_t)(m0 + r) * N + n0 + c4);
  tile[r][c4+0] = v[0]; tile[r][c4+1] = v[1];
  tile[r][c4+2] = v[2]; tile[r][c4+3] = v[3];
  __syncthreads();
  us4 o;
  o[0] = f2bf(tile[c4+0][r]); o[1] = f2bf(tile[c4+1][r]);
  o[2] = f2bf(tile[c4+2][r]); o[3] = f2bf(tile[c4+3][r]);
  *(us4*)(d + (size_t)(n0 + r) * M + m0 + c4) = o;
}

// ---------------- router: logits (fp64 lane-acc), top-2, renorm ------------
__global__ __launch_bounds__(256) void k_router(const float* __restrict__ x,
                                                const float* __restrict__ rw,
                                                int* __restrict__ topki,
                                                float* __restrict__ topkw) {
  __shared__ float wlds[8 * 1024];                   // 32 KB fp32
  int tid = threadIdx.x;
  #pragma unroll
  for (int i = 0; i < 8; ++i)
    ((f32x4*)wlds)[tid + i * 256] = ((const f32x4*)rw)[tid + i * 256];
  __syncthreads();

  int wv = tid >> 6, lane = tid & 63;
  int t = blockIdx.x * 4 + wv;
  const f32x4* xr = (const f32x4*)(x + (size_t)t * DDIM);
  f32x4 xv[4];
  #pragma unroll
  for (int j = 0; j < 4; ++j) xv[j] = xr[j * 64 + lane];
  double xd[16];
  #pragma unroll
  for (int j = 0; j < 4; ++j) {
    xd[j*4+0] = xv[j][0]; xd[j*4+1] = xv[j][1];
    xd[j*4+2] = xv[j][2]; xd[j*4+3] = xv[j][3];
  }
  float pf[8];
  #pragma unroll
  for (int e = 0; e < 8; ++e) {
    double acc = 0.0;
    #pragma unroll
    for (int j = 0; j < 4; ++j) {
      f32x4 wv4 = ((const f32x4*)(wlds + e * 1024))[j * 64 + lane];
      acc = fma((double)wv4[0], xd[j*4+0], acc);
      acc = fma((double)wv4[1], xd[j*4+1], acc);
      acc = fma((double)wv4[2], xd[j*4+2], acc);
      acc = fma((double)wv4[3], xd[j*4+3], acc);
    }
    pf[e] = (float)acc;
  }
  #pragma unroll
  for (int e = 0; e < 8; ++e) {
    #pragma unroll
    for (int off = 32; off >= 1; off >>= 1)
      pf[e] += __shfl_xor(pf[e], off, 64);
  }
  if (lane == 0) {
    int i1 = 0;
    #pragma unroll
    for (int e2 = 1; e2 < 8; ++e2) if (pf[e2] > pf[i1]) i1 = e2;
    int i2 = (i1 == 0) ? 1 : 0;
    #pragma unroll
    for (int e2 = 0; e2 < 8; ++e2) if (e2 != i1 && pf[e2] > pf[i2]) i2 = e2;
    float d21 = pf[i2] - pf[i1];
    float e1  = __expf(d21);
    float s   = 1.f + e1;
    topki[2*t]   = i1;       topki[2*t+1] = i2;
    topkw[2*t]   = 1.f / s;  topkw[2*t+1] = e1 / s;
  }
}

// -------- histogram of expert assignments (LDS-aggregated) -----------------
__global__ __launch_bounds__(256) void k_count(const int* __restrict__ topki,
                                               int* __restrict__ ctrs) {
  __shared__ int h[8];
  if (threadIdx.x < 8) h[threadIdx.x] = 0;
  __syncthreads();
  int i = blockIdx.x * 256 + threadIdx.x;
  atomicAdd(&h[topki[i]], 1);
  __syncthreads();
  if (threadIdx.x < 8) atomicAdd(&ctrs[threadIdx.x], h[threadIdx.x]);
}

// ctrs layout (ints): [0..7]=counts  [8..16]=offsets  [17..24]=pos
__global__ void k_scan(int* __restrict__ ctrs) {
  if (threadIdx.x == 0 && blockIdx.x == 0) {
    ctrs[8] = 0;
    #pragma unroll
    for (int e = 0; e < 8; ++e) ctrs[9 + e] = ctrs[8 + e] + ctrs[e];
    #pragma unroll
    for (int e = 0; e < 8; ++e) ctrs[17 + e] = 0;
  }
}

// -------- scatter with block-aggregated reservations -----------------------
__global__ __launch_bounds__(256) void k_scatter(const int* __restrict__ topki,
                                                 const float* __restrict__ topkw,
                                                 int* __restrict__ ctrs,
                                                 int* __restrict__ at,
                                                 float* __restrict__ aw) {
  __shared__ int lc[8], base[8];
  int tid = threadIdx.x;
  if (tid < 8) lc[tid] = 0;
  __syncthreads();
  int t = blockIdx.x * 256 + tid;
  int e0 = topki[2*t], e1 = topki[2*t+1];
  int r0 = atomicAdd(&lc[e0], 1);
  int r1 = atomicAdd(&lc[e1], 1);
  __syncthreads();
  if (tid < 8) base[tid] = atomicAdd(&ctrs[17 + tid], lc[tid]);
  __syncthreads();
  int a0 = ctrs[8 + e0] + base[e0] + r0;
  int a1 = ctrs[8 + e1] + base[e1] + r1;
  at[a0] = t; aw[a0] = topkw[2*t];
  at[a1] = t; aw[a1] = topkw[2*t+1];
}

// -------- grouped GEMM 1: h = silu(x@wg) * (x@wu) --------------------------
// 256x128 tile, BK=64, 8 waves @64x64(g)+64x64(u), double-buffered
// global_load_lds(16B) prefetch (2-phase), XOR-swizzled ds_read_b128.
__global__ __launch_bounds__(512, 2) void k_gateup(
    const unsigned short* __restrict__ xb,   // [T][D] bf16
    const unsigned short* __restrict__ wgt,  // [E][F][D] bf16 (transposed)
    const unsigned short* __restrict__ wut,  // [E][F][D]
    const int* __restrict__ at,
    const int* __restrict__ ctrs,
    unsigned short* __restrict__ h) {        // [2T][F] bf16
  int e    = blockIdx.z;
  int seg0 = ctrs[8 + e];
  int cnt  = ctrs[9 + e] - seg0;
  int row0 = blockIdx.y * 256;
  if (row0 >= cnt) return;
  int f0 = blockIdx.x * 128;

  __shared__ unsigned short lA [2][256 * 64];   // 2x32 KB (linear gload dest)
  __shared__ unsigned short lBg[2][128 * 64];   // 2x16 KB
  __shared__ unsigned short lBu[2][128 * 64];   // 2x16 KB
  __shared__ int s_tok[256];

  int tid = threadIdx.x;
  if (tid < 256) {
    int rg = row0 + tid;
    s_tok[tid] = at[seg0 + ((rg < cnt) ? rg : 0)];  // clamp ragged tail
  }
  __syncthreads();

  // staging: lA rounds i=0..3 rows i*64+(tid>>3); lB rounds j=0..1.
  // LDS slot holds global 16B-unit (u ^ (row&7))  [involution]
  const unsigned short* aSrc[4];
  size_t bOff[2];
  #pragma unroll
  for (int i = 0; i < 4; ++i) {
    int row = i * 64 + (tid >> 3);
    int su  = (tid & 7) ^ (row & 7);
    aSrc[i] = xb + (size_t)s_tok[row] * DDIM + su * 8;
  }
  #pragma unroll
  for (int j = 0; j < 2; ++j) {
    int row = j * 64 + (tid >> 3);
    int su  = (tid & 7) ^ (row & 7);
    bOff[j] = (size_t)row * DDIM + su * 8;
  }
  const unsigned short* bgBase = wgt + ((size_t)e * FDIM + f0) * DDIM;
  const unsigned short* buBase = wut + ((size_t)e * FDIM + f0) * DDIM;

  int w = tid >> 6, lane = tid & 63;
  int wr = (w >> 1) * 64, wc = (w & 1) * 64;   // 4x2 wave grid

  f32x4 zero = {0.f, 0.f, 0.f, 0.f};
  f32x4 accg[4][4], accu[4][4];
  #pragma unroll
  for (int mt = 0; mt < 4; ++mt)
    #pragma unroll
    for (int nt = 0; nt < 4; ++nt) { accg[mt][nt] = zero; accu[mt][nt] = zero; }

  // prologue: stage K-step 0 into buf 0
  #pragma unroll
  for (int i = 0; i < 4; ++i) gload16(aSrc[i], &lA[0][(i * 512 + tid) * 8]);
  #pragma unroll
  for (int j = 0; j < 2; ++j) {
    gload16(bgBase + bOff[j], &lBg[0][(j * 512 + tid) * 8]);
    gload16(buBase + bOff[j], &lBu[0][(j * 512 + tid) * 8]);
  }
  __syncthreads();

  int cur = 0;
  for (int ks = 0; ks < DDIM / 64; ++ks) {
    if (ks + 1 < DDIM / 64) {                   // prefetch next K-step
      int k1 = (ks + 1) * 64;
      int nx = cur ^ 1;
      #pragma unroll
      for (int i = 0; i < 4; ++i) gload16(aSrc[i] + k1, &lA[nx][(i * 512 + tid) * 8]);
      #pragma unroll
      for (int j = 0; j < 2; ++j) {
        gload16(bgBase + bOff[j] + k1, &lBg[nx][(j * 512 + tid) * 8]);
        gload16(buBase + bOff[j] + k1, &lBu[nx][(j * 512 + tid) * 8]);
      }
    }
    #pragma unroll
    for (int kk = 0; kk < 2; ++kk) {
      bf16x8 af[4];
      #pragma unroll
      for (int mt = 0; mt < 4; ++mt) {
        int ar = wr + mt * 16 + (lane & 15);
        int au = (kk * 4 + (lane >> 4)) ^ (ar & 7);
        af[mt] = *(const bf16x8*)&lA[cur][(ar * 8 + au) * 8];
      }
      #pragma unroll
      for (int nt = 0; nt < 4; ++nt) {
        int br = wc + nt * 16 + (lane & 15);
        int bu = (kk * 4 + (lane >> 4)) ^ (br & 7);
        bf16x8 bg = *(const bf16x8*)&lBg[cur][(br * 8 + bu) * 8];
        bf16x8 bv = *(const bf16x8*)&lBu[cur][(br * 8 + bu) * 8];
        #pragma unroll
        for (int mt = 0; mt < 4; ++mt) {
          accg[mt][nt] = __builtin_amdgcn_mfma_f32_16x16x32_bf16(af[mt], bg, accg[mt][nt], 0, 0, 0);
          accu[mt][nt] = __builtin_amdgcn_mfma_f32_16x16x32_bf16(af[mt], bv, accu[mt][nt], 0, 0, 0);
        }
      }
    }
    __syncthreads();                            // drains prefetch + ds_reads
    cur ^= 1;
  }
  // epilogue: silu(g)*u -> h  (C layout: col=lane&15, row=(lane>>4)*4+j)
  #pragma unroll
  for (int mt = 0; mt < 4; ++mt) {
    #pragma unroll
    for (int nt = 0; nt < 4; ++nt) {
      #pragma unroll
      for (int j = 0; j < 4; ++j) {
        int rl = wr + mt * 16 + (lane >> 4) * 4 + j;
        if (row0 + rl < cnt) {
          float g = accg[mt][nt][j], u = accu[mt][nt][j];
          float hv = g * (1.f / (1.f + __expf(-g))) * u;
          h[(size_t)(seg0 + row0 + rl) * FDIM + f0 + wc + nt * 16 + (lane & 15)] = f2bf(hv);
        }
      }
    }
  }
}

// -------- grouped GEMM 2: out[tok] += w * (h @ w_down[e]) ------------------
// 256x256 tile, BK=64, 8 waves @64x128, double-buffered prefetch.
__global__ __launch_bounds__(512, 2) void k_down(
    const unsigned short* __restrict__ h,    // [2T][F] bf16
    const unsigned short* __restrict__ wdt,  // [E][D][F] bf16 (transposed)
    const int* __restrict__ at,
    const float* __restrict__ aw,
    const int* __restrict__ ctrs,
    float* __restrict__ out) {               // [T][D] fp32 (zeroed)
  int e    = blockIdx.z;
  int seg0 = ctrs[8 + e];
  int cnt  = ctrs[9 + e] - seg0;
  int row0 = blockIdx.y * 256;
  if (row0 >= cnt) return;
  int d0 = blockIdx.x * 256;

  __shared__ unsigned short lA[2][256 * 64];   // 2x32 KB
  __shared__ unsigned short lB[2][256 * 64];   // 2x32 KB
  __shared__ int   s_tok[256];
  __shared__ float s_w[256];

  int tid = threadIdx.x;
  if (tid < 256) {
    int rg = row0 + tid;
    int a  = seg0 + ((rg < cnt) ? rg : 0);
    s_tok[tid] = at[a];
    s_w[tid]   = aw[a];
  }
  __syncthreads();

  const unsigned short* aSrc[4];
  size_t bOff[4];
  #pragma unroll
  for (int i = 0; i < 4; ++i) {
    int row = i * 64 + (tid >> 3);
    int su  = (tid & 7) ^ (row & 7);
    int rr  = (row0 + row < cnt) ? row0 + row : 0;        // clamp (OOB!)
    aSrc[i] = h + (size_t)(seg0 + rr) * FDIM + su * 8;
    bOff[i] = (size_t)row * FDIM + su * 8;
  }
  const unsigned short* bBase = wdt + ((size_t)e * DDIM + d0) * FDIM;

  int w = tid >> 6, lane = tid & 63;
  int wr = (w >> 1) * 64, wc = (w & 1) * 128;  // 4x2 waves, wave = 64x128

  f32x4 zero = {0.f, 0.f, 0.f, 0.f};
  f32x4 acc[4][8];
  #pragma unroll
  for (int mt = 0; mt < 4; ++mt)
    #pragma unroll
    for (int nt = 0; nt < 8; ++nt) acc[mt][nt] = zero;

  #pragma unroll
  for (int i = 0; i < 4; ++i) {
    gload16(aSrc[i],         &lA[0][(i * 512 + tid) * 8]);
    gload16(bBase + bOff[i], &lB[0][(i * 512 + tid) * 8]);
  }
  __syncthreads();

  int cur = 0;
  for (int ks = 0; ks < FDIM / 64; ++ks) {
    if (ks + 1 < FDIM / 64) {
      int k1 = (ks + 1) * 64;
      int nx = cur ^ 1;
      #pragma unroll
      for (int i = 0; i < 4; ++i) {
        gload16(aSrc[i] + k1,         &lA[nx][(i * 512 + tid) * 8]);
        gload16(bBase + bOff[i] + k1, &lB[nx][(i * 512 + tid) * 8]);
      }
    }
    #pragma unroll
    for (int kk = 0; kk < 2; ++kk) {
      bf16x8 af[4];
      #pragma unroll
      for (int mt = 0; mt < 4; ++mt) {
        int ar = wr + mt * 16 + (lane & 15);
        int au = (kk * 4 + (lane >> 4)) ^ (ar & 7);
        af[mt] = *(const bf16x8*)&lA[cur][(ar * 8 + au) * 8];
      }
      #pragma unroll
      for (int nt = 0; nt < 8; ++nt) {
        int br = wc + nt * 16 + (lane & 15);
        int bu = (kk * 4 + (lane >> 4)) ^ (br & 7);
        bf16x8 bf = *(const bf16x8*)&lB[cur][(br * 8 + bu) * 8];
        #pragma unroll
        for (int mt = 0; mt < 4; ++mt)
          acc[mt][nt] = __builtin_amdgcn_mfma_f32_16x16x32_bf16(af[mt], bf, acc[mt][nt], 0, 0, 0);
      }
    }
    __syncthreads();
    cur ^= 1;
  }
  #pragma unroll
  for (int mt = 0; mt < 4; ++mt) {
    #pragma unroll
    for (int nt = 0; nt < 8; ++nt) {
      #pragma unroll
      for (int j = 0; j < 4; ++j) {
        int rl = wr + mt * 16 + (lane >> 4) * 4 + j;
        if (row0 + rl < cnt) {
          float v = acc[mt][nt][j] * s_w[rl];
          atomicAdd(out + (size_t)s_tok[rl] * DDIM + d0 + wc + nt * 16 + (lane & 15), v);
        }
      }
    }
  }
}

// ---------------------------------------------------------------------------
extern "C" void kernel_launch(void* const* d_in, const int* in_sizes, int n_in,
                              void* d_out, int out_size, void* d_ws, size_t ws_size,
                              hipStream_t stream) {
  (void)in_sizes; (void)n_in; (void)ws_size;
  const float* x  = (const float*)d_in[0];
  const float* rw = (const float*)d_in[1];
  const float* wg = (const float*)d_in[2];
  const float* wu = (const float*)d_in[3];
  const float* wd = (const float*)d_in[4];
  float* out = (float*)d_out;

  // ws layout (bytes): ~59 MB
  char* ws = (char*)d_ws;
  unsigned short* xb  = (unsigned short*)(ws + 0);          // 16,777,216  [T][D] bf16
  unsigned short* wgt = (unsigned short*)(ws + 16777216);   //  8,388,608  [E][F][D]
  unsigned short* wut = (unsigned short*)(ws + 25165824);   //  8,388,608
  unsigned short* wdt = (unsigned short*)(ws + 33554432);   //  8,388,608  [E][D][F]
  unsigned short* hbuf= (unsigned short*)(ws + 41943040);   // 16,777,216  [2T][F]
  float* topkw = (float*)(ws + 58720256);                   // 65,536
  int*   topki = (int*)  (ws + 58785792);                   // 65,536
  int*   at    = (int*)  (ws + 58851328);                   // 65,536
  float* aw    = (float*)(ws + 58916864);                   // 65,536
  int*   ctrs  = (int*)  (ws + 58982400);                   // 256

  hipMemsetAsync(ctrs, 0, 256, stream);
  hipMemsetAsync(out, 0, (size_t)out_size * sizeof(float), stream);

  k_cvt_x<<<4096, 256, 0, stream>>>(x, xb);
  k_tcvt <<<dim3(16, 32, 8), 256, 0, stream>>>(wg, wgt, 1024, 512);
  k_tcvt <<<dim3(16, 32, 8), 256, 0, stream>>>(wu, wut, 1024, 512);
  k_tcvt <<<dim3(32, 16, 8), 256, 0, stream>>>(wd, wdt, 512, 1024);
  k_router<<<2048, 256, 0, stream>>>(x, rw, topki, topkw);
  k_count <<<64, 256, 0, stream>>>(topki, ctrs);
  k_scan  <<<1, 64, 0, stream>>>(ctrs);
  k_scatter<<<32, 256, 0, stream>>>(topki, topkw, ctrs, at, aw);
  k_gateup<<<dim3(4, 64, 8), 512, 0, stream>>>(xb, wgt, wut, at, ctrs, hbuf);
  k_down  <<<dim3(4, 64, 8), 512, 0, stream>>>(hbuf, wdt, at, aw, ctrs, out);
}

// Round 5
// 272.254 us; speedup vs baseline: 2.3648x; 1.1247x over previous
//
#include <hip/hip_runtime.h>
#include <hip/hip_bf16.h>

// MoE top-2 router + grouped SwiGLU experts, MI355X gfx950.
// T=8192 tokens, D=1024, E=8, F=512, top-k=2. fp32 in/out, bf16 MFMA compute.

typedef __attribute__((ext_vector_type(4))) float  f32x4;
typedef __attribute__((ext_vector_type(8))) unsigned short us8;
typedef __attribute__((ext_vector_type(4))) unsigned short us4;
typedef __bf16 bf16_t;
typedef __attribute__((ext_vector_type(8))) bf16_t bf16x8;

#define TTOK 8192
#define DDIM 1024
#define EEXP 8
#define FDIM 512

__device__ __forceinline__ unsigned short f2bf(float f) {
  unsigned int u = __float_as_uint(f);
  u = (u + 0x7FFFu + ((u >> 16) & 1u)) >> 16;   // RNE
  return (unsigned short)u;
}

__device__ __forceinline__ float bf2f(unsigned short u) {
  return __uint_as_float((unsigned int)u << 16);
}

__device__ __forceinline__ void gload16(const void* g, void* l) {
  __builtin_amdgcn_global_load_lds(
      (const __attribute__((address_space(1))) void*)g,
      (__attribute__((address_space(3))) void*)l, 16, 0, 0);
}

// ---- transpose+convert: src fp32 [e][M][N] -> dst bf16 [e][N][M] ----
__global__ __launch_bounds__(256) void k_tcvt(const float* __restrict__ src,
                                              unsigned short* __restrict__ dst,
                                              int M, int N) {
  __shared__ float tile[32][33];
  int e  = blockIdx.z;
  int m0 = blockIdx.y * 32, n0 = blockIdx.x * 32;
  const float* s = src + (size_t)e * M * N;
  unsigned short* d = dst + (size_t)e * M * N;
  int r  = threadIdx.x >> 3;
  int c4 = (threadIdx.x & 7) * 4;
  f32x4 v = *(const f32x4*)(s + (size_t)(m0 + r) * N + n0 + c4);
  tile[r][c4+0] = v[0]; tile[r][c4+1] = v[1];
  tile[r][c4+2] = v[2]; tile[r][c4+3] = v[3];
  __syncthreads();
  us4 o;
  o[0] = f2bf(tile[c4+0][r]); o[1] = f2bf(tile[c4+1][r]);
  o[2] = f2bf(tile[c4+2][r]); o[3] = f2bf(tile[c4+3][r]);
  *(us4*)(d + (size_t)(n0 + r) * M + m0 + c4) = o;
}

// ---- router: logits (fp64 lane-acc), top-2, renorm; fused x->bf16 ---------
__global__ __launch_bounds__(256) void k_router(const float* __restrict__ x,
                                                const float* __restrict__ rw,
                                                unsigned short* __restrict__ xb,
                                                int* __restrict__ topki,
                                                float* __restrict__ topkw) {
  __shared__ float wlds[8 * 1024];                   // 32 KB fp32
  int tid = threadIdx.x;
  #pragma unroll
  for (int i = 0; i < 8; ++i)
    ((f32x4*)wlds)[tid + i * 256] = ((const f32x4*)rw)[tid + i * 256];
  __syncthreads();

  int wv = tid >> 6, lane = tid & 63;
  int t = blockIdx.x * 4 + wv;
  const f32x4* xr = (const f32x4*)(x + (size_t)t * DDIM);
  f32x4 xv[4];
  #pragma unroll
  for (int j = 0; j < 4; ++j) xv[j] = xr[j * 64 + lane];
  // fused: write bf16 copy of x (same coalesced layout)
  #pragma unroll
  for (int j = 0; j < 4; ++j) {
    us4 o;
    o[0] = f2bf(xv[j][0]); o[1] = f2bf(xv[j][1]);
    o[2] = f2bf(xv[j][2]); o[3] = f2bf(xv[j][3]);
    *(us4*)(xb + (size_t)t * DDIM + (j * 64 + lane) * 4) = o;
  }
  double xd[16];
  #pragma unroll
  for (int j = 0; j < 4; ++j) {
    xd[j*4+0] = xv[j][0]; xd[j*4+1] = xv[j][1];
    xd[j*4+2] = xv[j][2]; xd[j*4+3] = xv[j][3];
  }
  float pf[8];
  #pragma unroll
  for (int e = 0; e < 8; ++e) {
    double acc = 0.0;
    #pragma unroll
    for (int j = 0; j < 4; ++j) {
      f32x4 wv4 = ((const f32x4*)(wlds + e * 1024))[j * 64 + lane];
      acc = fma((double)wv4[0], xd[j*4+0], acc);
      acc = fma((double)wv4[1], xd[j*4+1], acc);
      acc = fma((double)wv4[2], xd[j*4+2], acc);
      acc = fma((double)wv4[3], xd[j*4+3], acc);
    }
    pf[e] = (float)acc;
  }
  #pragma unroll
  for (int e = 0; e < 8; ++e) {
    #pragma unroll
    for (int off = 32; off >= 1; off >>= 1)
      pf[e] += __shfl_xor(pf[e], off, 64);
  }
  if (lane == 0) {
    int i1 = 0;
    #pragma unroll
    for (int e2 = 1; e2 < 8; ++e2) if (pf[e2] > pf[i1]) i1 = e2;
    int i2 = (i1 == 0) ? 1 : 0;
    #pragma unroll
    for (int e2 = 0; e2 < 8; ++e2) if (e2 != i1 && pf[e2] > pf[i2]) i2 = e2;
    float d21 = pf[i2] - pf[i1];
    float e1  = __expf(d21);
    float s   = 1.f + e1;
    topki[2*t]   = i1;       topki[2*t+1] = i2;
    topkw[2*t]   = 1.f / s;  topkw[2*t+1] = e1 / s;
  }
}

// -------- histogram of expert assignments (LDS-aggregated) -----------------
__global__ __launch_bounds__(256) void k_count(const int* __restrict__ topki,
                                               int* __restrict__ ctrs) {
  __shared__ int h[8];
  if (threadIdx.x < 8) h[threadIdx.x] = 0;
  __syncthreads();
  int i = blockIdx.x * 256 + threadIdx.x;
  atomicAdd(&h[topki[i]], 1);
  __syncthreads();
  if (threadIdx.x < 8) atomicAdd(&ctrs[threadIdx.x], h[threadIdx.x]);
}

// ctrs layout (ints): [0..7]=counts  [8..16]=offsets  [17..24]=pos
__global__ void k_scan(int* __restrict__ ctrs) {
  if (threadIdx.x == 0 && blockIdx.x == 0) {
    ctrs[8] = 0;
    #pragma unroll
    for (int e = 0; e < 8; ++e) ctrs[9 + e] = ctrs[8 + e] + ctrs[e];
    #pragma unroll
    for (int e = 0; e < 8; ++e) ctrs[17 + e] = 0;
  }
}

// -------- scatter + inverse map (pos) --------------------------------------
__global__ __launch_bounds__(256) void k_scatter(const int* __restrict__ topki,
                                                 const float* __restrict__ topkw,
                                                 int* __restrict__ ctrs,
                                                 int* __restrict__ at,
                                                 float* __restrict__ aw,
                                                 int* __restrict__ pos) {
  __shared__ int lc[8], base[8];
  int tid = threadIdx.x;
  if (tid < 8) lc[tid] = 0;
  __syncthreads();
  int t = blockIdx.x * 256 + tid;
  int e0 = topki[2*t], e1 = topki[2*t+1];
  int r0 = atomicAdd(&lc[e0], 1);
  int r1 = atomicAdd(&lc[e1], 1);
  __syncthreads();
  if (tid < 8) base[tid] = atomicAdd(&ctrs[17 + tid], lc[tid]);
  __syncthreads();
  int a0 = ctrs[8 + e0] + base[e0] + r0;
  int a1 = ctrs[8 + e1] + base[e1] + r1;
  at[a0] = t; aw[a0] = topkw[2*t];
  at[a1] = t; aw[a1] = topkw[2*t+1];
  pos[2*t] = a0; pos[2*t+1] = a1;
}

// -------- grouped GEMM 1: h = silu(x@wg) * (x@wu) --------------------------
// 256x128 tile, BK=64, 8 waves, double-buffered gload_lds(16B) prefetch,
// XOR-swizzled ds_read_b128.
__global__ __launch_bounds__(512, 2) void k_gateup(
    const unsigned short* __restrict__ xb,   // [T][D] bf16
    const unsigned short* __restrict__ wgt,  // [E][F][D] bf16 (transposed)
    const unsigned short* __restrict__ wut,  // [E][F][D]
    const int* __restrict__ at,
    const int* __restrict__ ctrs,
    unsigned short* __restrict__ h) {        // [2T][F] bf16
  int e    = blockIdx.z;
  int seg0 = ctrs[8 + e];
  int cnt  = ctrs[9 + e] - seg0;
  int row0 = blockIdx.y * 256;
  if (row0 >= cnt) return;
  int f0 = blockIdx.x * 128;

  __shared__ unsigned short lA [2][256 * 64];   // 2x32 KB (linear gload dest)
  __shared__ unsigned short lBg[2][128 * 64];   // 2x16 KB
  __shared__ unsigned short lBu[2][128 * 64];   // 2x16 KB
  __shared__ int s_tok[256];

  int tid = threadIdx.x;
  if (tid < 256) {
    int rg = row0 + tid;
    s_tok[tid] = at[seg0 + ((rg < cnt) ? rg : 0)];  // clamp ragged tail
  }
  __syncthreads();

  const unsigned short* aSrc[4];
  size_t bOff[2];
  #pragma unroll
  for (int i = 0; i < 4; ++i) {
    int row = i * 64 + (tid >> 3);
    int su  = (tid & 7) ^ (row & 7);
    aSrc[i] = xb + (size_t)s_tok[row] * DDIM + su * 8;
  }
  #pragma unroll
  for (int j = 0; j < 2; ++j) {
    int row = j * 64 + (tid >> 3);
    int su  = (tid & 7) ^ (row & 7);
    bOff[j] = (size_t)row * DDIM + su * 8;
  }
  const unsigned short* bgBase = wgt + ((size_t)e * FDIM + f0) * DDIM;
  const unsigned short* buBase = wut + ((size_t)e * FDIM + f0) * DDIM;

  int w = tid >> 6, lane = tid & 63;
  int wr = (w >> 1) * 64, wc = (w & 1) * 64;   // 4x2 wave grid

  f32x4 zero = {0.f, 0.f, 0.f, 0.f};
  f32x4 accg[4][4], accu[4][4];
  #pragma unroll
  for (int mt = 0; mt < 4; ++mt)
    #pragma unroll
    for (int nt = 0; nt < 4; ++nt) { accg[mt][nt] = zero; accu[mt][nt] = zero; }

  #pragma unroll
  for (int i = 0; i < 4; ++i) gload16(aSrc[i], &lA[0][(i * 512 + tid) * 8]);
  #pragma unroll
  for (int j = 0; j < 2; ++j) {
    gload16(bgBase + bOff[j], &lBg[0][(j * 512 + tid) * 8]);
    gload16(buBase + bOff[j], &lBu[0][(j * 512 + tid) * 8]);
  }
  __syncthreads();

  int cur = 0;
  for (int ks = 0; ks < DDIM / 64; ++ks) {
    if (ks + 1 < DDIM / 64) {                   // prefetch next K-step
      int k1 = (ks + 1) * 64;
      int nx = cur ^ 1;
      #pragma unroll
      for (int i = 0; i < 4; ++i) gload16(aSrc[i] + k1, &lA[nx][(i * 512 + tid) * 8]);
      #pragma unroll
      for (int j = 0; j < 2; ++j) {
        gload16(bgBase + bOff[j] + k1, &lBg[nx][(j * 512 + tid) * 8]);
        gload16(buBase + bOff[j] + k1, &lBu[nx][(j * 512 + tid) * 8]);
      }
    }
    #pragma unroll
    for (int kk = 0; kk < 2; ++kk) {
      bf16x8 af[4];
      #pragma unroll
      for (int mt = 0; mt < 4; ++mt) {
        int ar = wr + mt * 16 + (lane & 15);
        int au = (kk * 4 + (lane >> 4)) ^ (ar & 7);
        af[mt] = *(const bf16x8*)&lA[cur][(ar * 8 + au) * 8];
      }
      #pragma unroll
      for (int nt = 0; nt < 4; ++nt) {
        int br = wc + nt * 16 + (lane & 15);
        int bu = (kk * 4 + (lane >> 4)) ^ (br & 7);
        bf16x8 bg = *(const bf16x8*)&lBg[cur][(br * 8 + bu) * 8];
        bf16x8 bv = *(const bf16x8*)&lBu[cur][(br * 8 + bu) * 8];
        #pragma unroll
        for (int mt = 0; mt < 4; ++mt) {
          accg[mt][nt] = __builtin_amdgcn_mfma_f32_16x16x32_bf16(af[mt], bg, accg[mt][nt], 0, 0, 0);
          accu[mt][nt] = __builtin_amdgcn_mfma_f32_16x16x32_bf16(af[mt], bv, accu[mt][nt], 0, 0, 0);
        }
      }
    }
    __syncthreads();
    cur ^= 1;
  }
  #pragma unroll
  for (int mt = 0; mt < 4; ++mt) {
    #pragma unroll
    for (int nt = 0; nt < 4; ++nt) {
      #pragma unroll
      for (int j = 0; j < 4; ++j) {
        int rl = wr + mt * 16 + (lane >> 4) * 4 + j;
        if (row0 + rl < cnt) {
          float g = accg[mt][nt][j], u = accu[mt][nt][j];
          float hv = g * (1.f / (1.f + __expf(-g))) * u;
          h[(size_t)(seg0 + row0 + rl) * FDIM + f0 + wc + nt * 16 + (lane & 15)] = f2bf(hv);
        }
      }
    }
  }
}

// -------- grouped GEMM 2: y2[a] = aw[a] * (h[a] @ w_down[e]), bf16 ---------
// 256x256 tile, BK=64, 8 waves @64x128, double-buffered prefetch. No atomics.
__global__ __launch_bounds__(512, 2) void k_down(
    const unsigned short* __restrict__ h,    // [2T][F] bf16
    const unsigned short* __restrict__ wdt,  // [E][D][F] bf16 (transposed)
    const float* __restrict__ aw,
    const int* __restrict__ ctrs,
    unsigned short* __restrict__ y2) {       // [2T][D] bf16 (weighted rows)
  int e    = blockIdx.z;
  int seg0 = ctrs[8 + e];
  int cnt  = ctrs[9 + e] - seg0;
  int row0 = blockIdx.y * 256;
  if (row0 >= cnt) return;
  int d0 = blockIdx.x * 256;

  __shared__ unsigned short lA[2][256 * 64];   // 2x32 KB
  __shared__ unsigned short lB[2][256 * 64];   // 2x32 KB
  __shared__ float s_w[256];

  int tid = threadIdx.x;
  if (tid < 256) {
    int rg = row0 + tid;
    s_w[tid] = aw[seg0 + ((rg < cnt) ? rg : 0)];
  }
  __syncthreads();

  const unsigned short* aSrc[4];
  size_t bOff[4];
  #pragma unroll
  for (int i = 0; i < 4; ++i) {
    int row = i * 64 + (tid >> 3);
    int su  = (tid & 7) ^ (row & 7);
    int rr  = (row0 + row < cnt) ? row0 + row : 0;        // clamp (OOB!)
    aSrc[i] = h + (size_t)(seg0 + rr) * FDIM + su * 8;
    bOff[i] = (size_t)row * FDIM + su * 8;
  }
  const unsigned short* bBase = wdt + ((size_t)e * DDIM + d0) * FDIM;

  int w = tid >> 6, lane = tid & 63;
  int wr = (w >> 1) * 64, wc = (w & 1) * 128;  // 4x2 waves, wave = 64x128

  f32x4 zero = {0.f, 0.f, 0.f, 0.f};
  f32x4 acc[4][8];
  #pragma unroll
  for (int mt = 0; mt < 4; ++mt)
    #pragma unroll
    for (int nt = 0; nt < 8; ++nt) acc[mt][nt] = zero;

  #pragma unroll
  for (int i = 0; i < 4; ++i) {
    gload16(aSrc[i],         &lA[0][(i * 512 + tid) * 8]);
    gload16(bBase + bOff[i], &lB[0][(i * 512 + tid) * 8]);
  }
  __syncthreads();

  int cur = 0;
  for (int ks = 0; ks < FDIM / 64; ++ks) {
    if (ks + 1 < FDIM / 64) {
      int k1 = (ks + 1) * 64;
      int nx = cur ^ 1;
      #pragma unroll
      for (int i = 0; i < 4; ++i) {
        gload16(aSrc[i] + k1,         &lA[nx][(i * 512 + tid) * 8]);
        gload16(bBase + bOff[i] + k1, &lB[nx][(i * 512 + tid) * 8]);
      }
    }
    #pragma unroll
    for (int kk = 0; kk < 2; ++kk) {
      bf16x8 af[4];
      #pragma unroll
      for (int mt = 0; mt < 4; ++mt) {
        int ar = wr + mt * 16 + (lane & 15);
        int au = (kk * 4 + (lane >> 4)) ^ (ar & 7);
        af[mt] = *(const bf16x8*)&lA[cur][(ar * 8 + au) * 8];
      }
      #pragma unroll
      for (int nt = 0; nt < 8; ++nt) {
        int br = wc + nt * 16 + (lane & 15);
        int bu = (kk * 4 + (lane >> 4)) ^ (br & 7);
        bf16x8 bf = *(const bf16x8*)&lB[cur][(br * 8 + bu) * 8];
        #pragma unroll
        for (int mt = 0; mt < 4; ++mt)
          acc[mt][nt] = __builtin_amdgcn_mfma_f32_16x16x32_bf16(af[mt], bf, acc[mt][nt], 0, 0, 0);
      }
    }
    __syncthreads();
    cur ^= 1;
  }
  // epilogue: weighted row -> bf16 plain stores (no atomics)
  #pragma unroll
  for (int mt = 0; mt < 4; ++mt) {
    #pragma unroll
    for (int nt = 0; nt < 8; ++nt) {
      #pragma unroll
      for (int j = 0; j < 4; ++j) {
        int rl = wr + mt * 16 + (lane >> 4) * 4 + j;
        if (row0 + rl < cnt) {
          float v = acc[mt][nt][j] * s_w[rl];
          y2[(size_t)(seg0 + row0 + rl) * DDIM + d0 + wc + nt * 16 + (lane & 15)] = f2bf(v);
        }
      }
    }
  }
}

// -------- combine: out[t] = y2[pos[2t]] + y2[pos[2t+1]] --------------------
__global__ __launch_bounds__(256) void k_combine(const unsigned short* __restrict__ y2,
                                                 const int* __restrict__ pos,
                                                 float* __restrict__ out) {
  int idx = blockIdx.x * 256 + threadIdx.x;    // one us8 (8 elems) per thread
  int t = idx >> 7;                            // D/8 = 128 chunks per token
  int c = idx & 127;
  int a0 = pos[2*t], a1 = pos[2*t+1];
  us8 v0 = *((const us8*)(y2 + (size_t)a0 * DDIM) + c);
  us8 v1 = *((const us8*)(y2 + (size_t)a1 * DDIM) + c);
  f32x4 o0, o1;
  #pragma unroll
  for (int m = 0; m < 4; ++m) o0[m] = bf2f(v0[m]) + bf2f(v1[m]);
  #pragma unroll
  for (int m = 0; m < 4; ++m) o1[m] = bf2f(v0[4+m]) + bf2f(v1[4+m]);
  f32x4* dst = (f32x4*)(out + (size_t)t * DDIM + c * 8);
  dst[0] = o0; dst[1] = o1;
}

// ---------------------------------------------------------------------------
extern "C" void kernel_launch(void* const* d_in, const int* in_sizes, int n_in,
                              void* d_out, int out_size, void* d_ws, size_t ws_size,
                              hipStream_t stream) {
  (void)in_sizes; (void)n_in; (void)ws_size; (void)out_size;
  const float* x  = (const float*)d_in[0];
  const float* rw = (const float*)d_in[1];
  const float* wg = (const float*)d_in[2];
  const float* wu = (const float*)d_in[3];
  const float* wd = (const float*)d_in[4];
  float* out = (float*)d_out;

  // ws layout (bytes), ~59.1 MB. y2 ALIASES xb+wgt+wut (dead after gateup;
  // strictly stream-ordered: k_down writes y2 only after gateup completes).
  char* ws = (char*)d_ws;
  unsigned short* xb  = (unsigned short*)(ws + 0);          // 16,777,216  [T][D] bf16
  unsigned short* wgt = (unsigned short*)(ws + 16777216);   //  8,388,608  [E][F][D]
  unsigned short* wut = (unsigned short*)(ws + 25165824);   //  8,388,608
  unsigned short* y2  = (unsigned short*)(ws + 0);          // 33,554,432  [2T][D] bf16 (alias)
  unsigned short* wdt = (unsigned short*)(ws + 33554432);   //  8,388,608  [E][D][F]
  unsigned short* hbuf= (unsigned short*)(ws + 41943040);   // 16,777,216  [2T][F]
  float* topkw = (float*)(ws + 58720256);                   // 65,536
  int*   topki = (int*)  (ws + 58785792);                   // 65,536
  int*   at    = (int*)  (ws + 58851328);                   // 65,536
  float* aw    = (float*)(ws + 58916864);                   // 65,536
  int*   ctrs  = (int*)  (ws + 58982400);                   // 256
  int*   pos   = (int*)  (ws + 58982656);                   // 65,536

  hipMemsetAsync(ctrs, 0, 256, stream);

  k_router<<<2048, 256, 0, stream>>>(x, rw, xb, topki, topkw);
  k_tcvt <<<dim3(16, 32, 8), 256, 0, stream>>>(wg, wgt, 1024, 512);
  k_tcvt <<<dim3(16, 32, 8), 256, 0, stream>>>(wu, wut, 1024, 512);
  k_tcvt <<<dim3(32, 16, 8), 256, 0, stream>>>(wd, wdt, 512, 1024);
  k_count <<<64, 256, 0, stream>>>(topki, ctrs);
  k_scan  <<<1, 64, 0, stream>>>(ctrs);
  k_scatter<<<32, 256, 0, stream>>>(topki, topkw, ctrs, at, aw, pos);
  k_gateup<<<dim3(4, 64, 8), 512, 0, stream>>>(xb, wgt, wut, at, ctrs, hbuf);
  k_down  <<<dim3(4, 64, 8), 512, 0, stream>>>(hbuf, wdt, aw, ctrs, y2);
  k_combine<<<4096, 256, 0, stream>>>(y2, pos, out);
}

// Round 6
// 264.784 us; speedup vs baseline: 2.4315x; 1.0282x over previous
//
#include <hip/hip_runtime.h>
#include <hip/hip_bf16.h>

// MoE top-2 router + grouped SwiGLU experts, MI355X gfx950.
// T=8192 tokens, D=1024, E=8, F=512, top-k=2. fp32 in/out, bf16 MFMA compute.

typedef __attribute__((ext_vector_type(4))) float  f32x4;
typedef __attribute__((ext_vector_type(8))) unsigned short us8;
typedef __attribute__((ext_vector_type(4))) unsigned short us4;
typedef __bf16 bf16_t;
typedef __attribute__((ext_vector_type(8))) bf16_t bf16x8;

#define TTOK 8192
#define DDIM 1024
#define EEXP 8
#define FDIM 512

#define LGKM0() asm volatile("s_waitcnt lgkmcnt(0)" ::: "memory")
#define SBAR()  __builtin_amdgcn_s_barrier()
#define SCHEDB() __builtin_amdgcn_sched_barrier(0)

__device__ __forceinline__ unsigned short f2bf(float f) {
  unsigned int u = __float_as_uint(f);
  u = (u + 0x7FFFu + ((u >> 16) & 1u)) >> 16;   // RNE
  return (unsigned short)u;
}

__device__ __forceinline__ float bf2f(unsigned short u) {
  return __uint_as_float((unsigned int)u << 16);
}

__device__ __forceinline__ void gload16(const void* g, void* l) {
  __builtin_amdgcn_global_load_lds(
      (const __attribute__((address_space(1))) void*)g,
      (__attribute__((address_space(3))) void*)l, 16, 0, 0);
}

// ---- transpose+convert: two fp32 [8][M][N] srcs -> bf16 [8][N][M] dsts ----
__global__ __launch_bounds__(256) void k_tcvt2(const float* __restrict__ s0,
                                               const float* __restrict__ s1,
                                               unsigned short* __restrict__ d0,
                                               unsigned short* __restrict__ d1,
                                               int M, int N) {
  __shared__ float tile[32][33];
  int zz = blockIdx.z;
  const float* src = (zz < 8) ? s0 : s1;
  unsigned short* dst = (zz < 8) ? d0 : d1;
  int e  = zz & 7;
  int m0 = blockIdx.y * 32, n0 = blockIdx.x * 32;
  const float* s = src + (size_t)e * M * N;
  unsigned short* d = dst + (size_t)e * M * N;
  int r  = threadIdx.x >> 3;
  int c4 = (threadIdx.x & 7) * 4;
  f32x4 v = *(const f32x4*)(s + (size_t)(m0 + r) * N + n0 + c4);
  tile[r][c4+0] = v[0]; tile[r][c4+1] = v[1];
  tile[r][c4+2] = v[2]; tile[r][c4+3] = v[3];
  __syncthreads();
  us4 o;
  o[0] = f2bf(tile[c4+0][r]); o[1] = f2bf(tile[c4+1][r]);
  o[2] = f2bf(tile[c4+2][r]); o[3] = f2bf(tile[c4+3][r]);
  *(us4*)(d + (size_t)(n0 + r) * M + m0 + c4) = o;
}

// ---- router: logits (fp64 lane-acc), top-2, renorm; fused x->bf16 ---------
__global__ __launch_bounds__(256) void k_router(const float* __restrict__ x,
                                                const float* __restrict__ rw,
                                                unsigned short* __restrict__ xb,
                                                int* __restrict__ topki,
                                                float* __restrict__ topkw) {
  __shared__ float wlds[8 * 1024];                   // 32 KB fp32
  int tid = threadIdx.x;
  #pragma unroll
  for (int i = 0; i < 8; ++i)
    ((f32x4*)wlds)[tid + i * 256] = ((const f32x4*)rw)[tid + i * 256];
  __syncthreads();

  int wv = tid >> 6, lane = tid & 63;
  int t = blockIdx.x * 4 + wv;
  const f32x4* xr = (const f32x4*)(x + (size_t)t * DDIM);
  f32x4 xv[4];
  #pragma unroll
  for (int j = 0; j < 4; ++j) xv[j] = xr[j * 64 + lane];
  #pragma unroll
  for (int j = 0; j < 4; ++j) {
    us4 o;
    o[0] = f2bf(xv[j][0]); o[1] = f2bf(xv[j][1]);
    o[2] = f2bf(xv[j][2]); o[3] = f2bf(xv[j][3]);
    *(us4*)(xb + (size_t)t * DDIM + (j * 64 + lane) * 4) = o;
  }
  double xd[16];
  #pragma unroll
  for (int j = 0; j < 4; ++j) {
    xd[j*4+0] = xv[j][0]; xd[j*4+1] = xv[j][1];
    xd[j*4+2] = xv[j][2]; xd[j*4+3] = xv[j][3];
  }
  float pf[8];
  #pragma unroll
  for (int e = 0; e < 8; ++e) {
    double acc = 0.0;
    #pragma unroll
    for (int j = 0; j < 4; ++j) {
      f32x4 wv4 = ((const f32x4*)(wlds + e * 1024))[j * 64 + lane];
      acc = fma((double)wv4[0], xd[j*4+0], acc);
      acc = fma((double)wv4[1], xd[j*4+1], acc);
      acc = fma((double)wv4[2], xd[j*4+2], acc);
      acc = fma((double)wv4[3], xd[j*4+3], acc);
    }
    pf[e] = (float)acc;
  }
  #pragma unroll
  for (int e = 0; e < 8; ++e) {
    #pragma unroll
    for (int off = 32; off >= 1; off >>= 1)
      pf[e] += __shfl_xor(pf[e], off, 64);
  }
  if (lane == 0) {
    int i1 = 0;
    #pragma unroll
    for (int e2 = 1; e2 < 8; ++e2) if (pf[e2] > pf[i1]) i1 = e2;
    int i2 = (i1 == 0) ? 1 : 0;
    #pragma unroll
    for (int e2 = 0; e2 < 8; ++e2) if (e2 != i1 && pf[e2] > pf[i2]) i2 = e2;
    float d21 = pf[i2] - pf[i1];
    float e1  = __expf(d21);
    float s   = 1.f + e1;
    topki[2*t]   = i1;       topki[2*t+1] = i2;
    topkw[2*t]   = 1.f / s;  topkw[2*t+1] = e1 / s;
  }
}

// -------- histogram of expert assignments (LDS-aggregated) -----------------
__global__ __launch_bounds__(256) void k_count(const int* __restrict__ topki,
                                               int* __restrict__ ctrs) {
  __shared__ int h[8];
  if (threadIdx.x < 8) h[threadIdx.x] = 0;
  __syncthreads();
  int i = blockIdx.x * 256 + threadIdx.x;
  atomicAdd(&h[topki[i]], 1);
  __syncthreads();
  if (threadIdx.x < 8) atomicAdd(&ctrs[threadIdx.x], h[threadIdx.x]);
}

// ctrs layout (ints): [0..7]=counts  [8..16]=offsets  [17..24]=pos
__global__ void k_scan(int* __restrict__ ctrs) {
  if (threadIdx.x == 0 && blockIdx.x == 0) {
    ctrs[8] = 0;
    #pragma unroll
    for (int e = 0; e < 8; ++e) ctrs[9 + e] = ctrs[8 + e] + ctrs[e];
    #pragma unroll
    for (int e = 0; e < 8; ++e) ctrs[17 + e] = 0;
  }
}

// -------- scatter + inverse map (pos) --------------------------------------
__global__ __launch_bounds__(256) void k_scatter(const int* __restrict__ topki,
                                                 const float* __restrict__ topkw,
                                                 int* __restrict__ ctrs,
                                                 int* __restrict__ at,
                                                 float* __restrict__ aw,
                                                 int* __restrict__ pos) {
  __shared__ int lc[8], base[8];
  int tid = threadIdx.x;
  if (tid < 8) lc[tid] = 0;
  __syncthreads();
  int t = blockIdx.x * 256 + tid;
  int e0 = topki[2*t], e1 = topki[2*t+1];
  int r0 = atomicAdd(&lc[e0], 1);
  int r1 = atomicAdd(&lc[e1], 1);
  __syncthreads();
  if (tid < 8) base[tid] = atomicAdd(&ctrs[17 + tid], lc[tid]);
  __syncthreads();
  int a0 = ctrs[8 + e0] + base[e0] + r0;
  int a1 = ctrs[8 + e1] + base[e1] + r1;
  at[a0] = t; aw[a0] = topkw[2*t];
  at[a1] = t; aw[a1] = topkw[2*t+1];
  pos[2*t] = a0; pos[2*t+1] = a1;
}

// -------- grouped GEMM 1: h = silu(x@wg) * (x@wu) --------------------------
// 256x128 tile, BK=64, 8 waves, double-buffered gload_lds(16B) with COUNTED
// vmcnt (prefetch stays in flight across barriers), XOR-swizzled ds_read_b128.
// 1-D grid 2048, XCD-chunked: expert e -> XCD e (weight slab L2-resident).
__global__ __launch_bounds__(512, 2) void k_gateup(
    const unsigned short* __restrict__ xb,   // [T][D] bf16
    const unsigned short* __restrict__ wgt,  // [E][F][D] bf16 (transposed)
    const unsigned short* __restrict__ wut,  // [E][F][D]
    const int* __restrict__ at,
    const int* __restrict__ ctrs,
    unsigned short* __restrict__ h) {        // [2T][F] bf16
  int bid = blockIdx.x;
  int swz = (bid & 7) * 256 + (bid >> 3);    // XCD-chunked (2048 % 8 == 0)
  int e   = swz >> 8;
  int yt  = (swz & 255) >> 2;
  int ft  = swz & 3;
  int seg0 = ctrs[8 + e];
  int cnt  = ctrs[9 + e] - seg0;
  int row0 = yt * 256;
  if (row0 >= cnt) return;
  int f0 = ft * 128;

  __shared__ unsigned short lA [2][256 * 64];   // 2x32 KB (linear gload dest)
  __shared__ unsigned short lBg[2][128 * 64];   // 2x16 KB
  __shared__ unsigned short lBu[2][128 * 64];   // 2x16 KB
  __shared__ int s_tok[256];

  int tid = threadIdx.x;
  if (tid < 256) {
    int rg = row0 + tid;
    s_tok[tid] = at[seg0 + ((rg < cnt) ? rg : 0)];  // clamp ragged tail
  }
  __syncthreads();

  const unsigned short* aSrc[4];
  size_t bOff[2];
  #pragma unroll
  for (int i = 0; i < 4; ++i) {
    int row = i * 64 + (tid >> 3);
    int su  = (tid & 7) ^ (row & 7);
    aSrc[i] = xb + (size_t)s_tok[row] * DDIM + su * 8;
  }
  #pragma unroll
  for (int j = 0; j < 2; ++j) {
    int row = j * 64 + (tid >> 3);
    int su  = (tid & 7) ^ (row & 7);
    bOff[j] = (size_t)row * DDIM + su * 8;
  }
  const unsigned short* bgBase = wgt + ((size_t)e * FDIM + f0) * DDIM;
  const unsigned short* buBase = wut + ((size_t)e * FDIM + f0) * DDIM;

  int w = tid >> 6, lane = tid & 63;
  int wr = (w >> 1) * 64, wc = (w & 1) * 64;   // 4x2 wave grid

  f32x4 zero = {0.f, 0.f, 0.f, 0.f};
  f32x4 accg[4][4], accu[4][4];
  #pragma unroll
  for (int mt = 0; mt < 4; ++mt)
    #pragma unroll
    for (int nt = 0; nt < 4; ++nt) { accg[mt][nt] = zero; accu[mt][nt] = zero; }

  // STAGE(buf, k0): 8 gload16 per thread (4 A + 2 Bg + 2 Bu)
#define GU_STAGE(B, K0) do {                                              \
    _Pragma("unroll")                                                     \
    for (int i = 0; i < 4; ++i) gload16(aSrc[i] + (K0), &lA[B][(i * 512 + tid) * 8]); \
    _Pragma("unroll")                                                     \
    for (int j = 0; j < 2; ++j) {                                         \
      gload16(bgBase + bOff[j] + (K0), &lBg[B][(j * 512 + tid) * 8]);     \
      gload16(buBase + bOff[j] + (K0), &lBu[B][(j * 512 + tid) * 8]);     \
    }                                                                     \
  } while (0)

  GU_STAGE(0, 0);                              // prologue (8 in flight)
  int cur = 0;
  for (int ks = 0; ks < DDIM / 64; ++ks) {
    if (ks + 1 < DDIM / 64) {
      GU_STAGE(cur ^ 1, (ks + 1) * 64);        // 16 in flight
      asm volatile("s_waitcnt vmcnt(8)" ::: "memory");  // wait cur's 8 only
    } else {
      asm volatile("s_waitcnt vmcnt(0)" ::: "memory");
    }
    SBAR(); SCHEDB();                          // all waves' cur writes landed
    #pragma unroll
    for (int kk = 0; kk < 2; ++kk) {
      bf16x8 af[4];
      #pragma unroll
      for (int mt = 0; mt < 4; ++mt) {
        int ar = wr + mt * 16 + (lane & 15);
        int au = (kk * 4 + (lane >> 4)) ^ (ar & 7);
        af[mt] = *(const bf16x8*)&lA[cur][(ar * 8 + au) * 8];
      }
      #pragma unroll
      for (int nt = 0; nt < 4; ++nt) {
        int br = wc + nt * 16 + (lane & 15);
        int bu = (kk * 4 + (lane >> 4)) ^ (br & 7);
        bf16x8 bg = *(const bf16x8*)&lBg[cur][(br * 8 + bu) * 8];
        bf16x8 bv = *(const bf16x8*)&lBu[cur][(br * 8 + bu) * 8];
        #pragma unroll
        for (int mt = 0; mt < 4; ++mt) {
          accg[mt][nt] = __builtin_amdgcn_mfma_f32_16x16x32_bf16(af[mt], bg, accg[mt][nt], 0, 0, 0);
          accu[mt][nt] = __builtin_amdgcn_mfma_f32_16x16x32_bf16(af[mt], bv, accu[mt][nt], 0, 0, 0);
        }
      }
    }
    LGKM0(); SCHEDB();                         // my ds_reads of cur done
    SBAR();                                    // gate next iter's overwrite
    cur ^= 1;
  }
#undef GU_STAGE
  // epilogue: silu(g)*u -> h  (C layout: col=lane&15, row=(lane>>4)*4+j)
  #pragma unroll
  for (int mt = 0; mt < 4; ++mt) {
    #pragma unroll
    for (int nt = 0; nt < 4; ++nt) {
      #pragma unroll
      for (int j = 0; j < 4; ++j) {
        int rl = wr + mt * 16 + (lane >> 4) * 4 + j;
        if (row0 + rl < cnt) {
          float g = accg[mt][nt][j], u = accu[mt][nt][j];
          float hv = g * (1.f / (1.f + __expf(-g))) * u;
          h[(size_t)(seg0 + row0 + rl) * FDIM + f0 + wc + nt * 16 + (lane & 15)] = f2bf(hv);
        }
      }
    }
  }
}

// -------- grouped GEMM 2: y2[a] = aw[a] * (h[a] @ w_down[e]), bf16 ---------
// 256x256 tile, BK=64, 8 waves @64x128, counted-vmcnt double buffer.
__global__ __launch_bounds__(512, 2) void k_down(
    const unsigned short* __restrict__ h,    // [2T][F] bf16
    const unsigned short* __restrict__ wdt,  // [E][D][F] bf16 (transposed)
    const float* __restrict__ aw,
    const int* __restrict__ ctrs,
    unsigned short* __restrict__ y2) {       // [2T][D] bf16 (weighted rows)
  int bid = blockIdx.x;
  int swz = (bid & 7) * 256 + (bid >> 3);    // XCD-chunked
  int e   = swz >> 8;
  int yt  = (swz & 255) >> 2;
  int dt  = swz & 3;
  int seg0 = ctrs[8 + e];
  int cnt  = ctrs[9 + e] - seg0;
  int row0 = yt * 256;
  if (row0 >= cnt) return;
  int d0 = dt * 256;

  __shared__ unsigned short lA[2][256 * 64];   // 2x32 KB
  __shared__ unsigned short lB[2][256 * 64];   // 2x32 KB
  __shared__ float s_w[256];

  int tid = threadIdx.x;
  if (tid < 256) {
    int rg = row0 + tid;
    s_w[tid] = aw[seg0 + ((rg < cnt) ? rg : 0)];
  }
  __syncthreads();

  const unsigned short* aSrc[4];
  size_t bOff[4];
  #pragma unroll
  for (int i = 0; i < 4; ++i) {
    int row = i * 64 + (tid >> 3);
    int su  = (tid & 7) ^ (row & 7);
    int rr  = (row0 + row < cnt) ? row0 + row : 0;        // clamp (OOB!)
    aSrc[i] = h + (size_t)(seg0 + rr) * FDIM + su * 8;
    bOff[i] = (size_t)row * FDIM + su * 8;
  }
  const unsigned short* bBase = wdt + ((size_t)e * DDIM + d0) * FDIM;

  int w = tid >> 6, lane = tid & 63;
  int wr = (w >> 1) * 64, wc = (w & 1) * 128;  // 4x2 waves, wave = 64x128

  f32x4 zero = {0.f, 0.f, 0.f, 0.f};
  f32x4 acc[4][8];
  #pragma unroll
  for (int mt = 0; mt < 4; ++mt)
    #pragma unroll
    for (int nt = 0; nt < 8; ++nt) acc[mt][nt] = zero;

#define DN_STAGE(B, K0) do {                                              \
    _Pragma("unroll")                                                     \
    for (int i = 0; i < 4; ++i) {                                         \
      gload16(aSrc[i] + (K0),         &lA[B][(i * 512 + tid) * 8]);       \
      gload16(bBase + bOff[i] + (K0), &lB[B][(i * 512 + tid) * 8]);       \
    }                                                                     \
  } while (0)

  DN_STAGE(0, 0);
  int cur = 0;
  for (int ks = 0; ks < FDIM / 64; ++ks) {
    if (ks + 1 < FDIM / 64) {
      DN_STAGE(cur ^ 1, (ks + 1) * 64);
      asm volatile("s_waitcnt vmcnt(8)" ::: "memory");
    } else {
      asm volatile("s_waitcnt vmcnt(0)" ::: "memory");
    }
    SBAR(); SCHEDB();
    #pragma unroll
    for (int kk = 0; kk < 2; ++kk) {
      bf16x8 af[4];
      #pragma unroll
      for (int mt = 0; mt < 4; ++mt) {
        int ar = wr + mt * 16 + (lane & 15);
        int au = (kk * 4 + (lane >> 4)) ^ (ar & 7);
        af[mt] = *(const bf16x8*)&lA[cur][(ar * 8 + au) * 8];
      }
      #pragma unroll
      for (int nt = 0; nt < 8; ++nt) {
        int br = wc + nt * 16 + (lane & 15);
        int bu = (kk * 4 + (lane >> 4)) ^ (br & 7);
        bf16x8 bf = *(const bf16x8*)&lB[cur][(br * 8 + bu) * 8];
        #pragma unroll
        for (int mt = 0; mt < 4; ++mt)
          acc[mt][nt] = __builtin_amdgcn_mfma_f32_16x16x32_bf16(af[mt], bf, acc[mt][nt], 0, 0, 0);
      }
    }
    LGKM0(); SCHEDB();
    SBAR();
    cur ^= 1;
  }
#undef DN_STAGE
  // epilogue: weighted row -> bf16 plain stores (no atomics)
  #pragma unroll
  for (int mt = 0; mt < 4; ++mt) {
    #pragma unroll
    for (int nt = 0; nt < 8; ++nt) {
      #pragma unroll
      for (int j = 0; j < 4; ++j) {
        int rl = wr + mt * 16 + (lane >> 4) * 4 + j;
        if (row0 + rl < cnt) {
          float v = acc[mt][nt][j] * s_w[rl];
          y2[(size_t)(seg0 + row0 + rl) * DDIM + d0 + wc + nt * 16 + (lane & 15)] = f2bf(v);
        }
      }
    }
  }
}

// -------- combine: out[t] = y2[pos[2t]] + y2[pos[2t+1]] --------------------
__global__ __launch_bounds__(256) void k_combine(const unsigned short* __restrict__ y2,
                                                 const int* __restrict__ pos,
                                                 float* __restrict__ out) {
  int idx = blockIdx.x * 256 + threadIdx.x;    // one us8 (8 elems) per thread
  int t = idx >> 7;                            // D/8 = 128 chunks per token
  int c = idx & 127;
  int a0 = pos[2*t], a1 = pos[2*t+1];
  us8 v0 = *((const us8*)(y2 + (size_t)a0 * DDIM) + c);
  us8 v1 = *((const us8*)(y2 + (size_t)a1 * DDIM) + c);
  f32x4 o0, o1;
  #pragma unroll
  for (int m = 0; m < 4; ++m) o0[m] = bf2f(v0[m]) + bf2f(v1[m]);
  #pragma unroll
  for (int m = 0; m < 4; ++m) o1[m] = bf2f(v0[4+m]) + bf2f(v1[4+m]);
  f32x4* dst = (f32x4*)(out + (size_t)t * DDIM + c * 8);
  dst[0] = o0; dst[1] = o1;
}

// ---------------------------------------------------------------------------
extern "C" void kernel_launch(void* const* d_in, const int* in_sizes, int n_in,
                              void* d_out, int out_size, void* d_ws, size_t ws_size,
                              hipStream_t stream) {
  (void)in_sizes; (void)n_in; (void)ws_size; (void)out_size;
  const float* x  = (const float*)d_in[0];
  const float* rw = (const float*)d_in[1];
  const float* wg = (const float*)d_in[2];
  const float* wu = (const float*)d_in[3];
  const float* wd = (const float*)d_in[4];
  float* out = (float*)d_out;

  // ws layout (bytes), ~59.1 MB. y2 ALIASES xb+wgt+wut (dead after gateup;
  // strictly stream-ordered: k_down writes y2 only after gateup completes).
  char* ws = (char*)d_ws;
  unsigned short* xb  = (unsigned short*)(ws + 0);          // 16,777,216  [T][D] bf16
  unsigned short* wgt = (unsigned short*)(ws + 16777216);   //  8,388,608  [E][F][D]
  unsigned short* wut = (unsigned short*)(ws + 25165824);   //  8,388,608
  unsigned short* y2  = (unsigned short*)(ws + 0);          // 33,554,432  [2T][D] bf16 (alias)
  unsigned short* wdt = (unsigned short*)(ws + 33554432);   //  8,388,608  [E][D][F]
  unsigned short* hbuf= (unsigned short*)(ws + 41943040);   // 16,777,216  [2T][F]
  float* topkw = (float*)(ws + 58720256);                   // 65,536
  int*   topki = (int*)  (ws + 58785792);                   // 65,536
  int*   at    = (int*)  (ws + 58851328);                   // 65,536
  float* aw    = (float*)(ws + 58916864);                   // 65,536
  int*   ctrs  = (int*)  (ws + 58982400);                   // 256
  int*   pos   = (int*)  (ws + 58982656);                   // 65,536

  hipMemsetAsync(ctrs, 0, 256, stream);

  k_router<<<2048, 256, 0, stream>>>(x, rw, xb, topki, topkw);
  k_tcvt2<<<dim3(16, 32, 16), 256, 0, stream>>>(wg, wu, wgt, wut, 1024, 512);
  k_tcvt2<<<dim3(32, 16, 8), 256, 0, stream>>>(wd, wd, wdt, wdt, 512, 1024);
  k_count <<<64, 256, 0, stream>>>(topki, ctrs);
  k_scan  <<<1, 64, 0, stream>>>(ctrs);
  k_scatter<<<32, 256, 0, stream>>>(topki, topkw, ctrs, at, aw, pos);
  k_gateup<<<2048, 512, 0, stream>>>(xb, wgt, wut, at, ctrs, hbuf);
  k_down  <<<2048, 512, 0, stream>>>(hbuf, wdt, aw, ctrs, y2);
  k_combine<<<4096, 256, 0, stream>>>(y2, pos, out);
}